// Round 3
// baseline (1928.156 us; speedup 1.0000x reference)
//
#include <hip/hip_runtime.h>
#include <cstdint>
#include <cstddef>

#define NN 60000
#define NE 960000
#define NB 32
#define FIN 38
#define HH 128

// Both siamese sides are processed in one launch per stage: blockIdx.y (or
// block index) selects the side; workspace buffers are [2][...] with per-side
// strides. Doubles occupancy and halves launch-chain depth vs per-side loops.

// ---------------------------------------------------------------- CSR build
__global__ __launch_bounds__(256) void k_hist(const int* __restrict__ ei0,
                                              const int* __restrict__ ei1,
                                              int* __restrict__ counts) {
  int s = blockIdx.y;
  const int* ei = s ? ei1 : ei0;
  int i = blockIdx.x * 256 + threadIdx.x;
  if (i < NE) atomicAdd(&counts[s * NN + ei[NE + i]], 1);
}

__global__ __launch_bounds__(1024) void k_scan(const int* __restrict__ counts_,
                                               int* __restrict__ rowptr_,
                                               int* __restrict__ cursor_) {
  int s = blockIdx.x;
  const int* counts = counts_ + (size_t)s * NN;
  int* rowptr = rowptr_ + (size_t)s * (NN + 1);
  int* cursor = cursor_ + (size_t)s * NN;
  __shared__ int sm[1024];
  const int C = 59;  // 1024*59 = 60416 >= NN
  int t = threadIdx.x;
  int base = t * C;
  int lsum = 0;
  for (int j = 0; j < C; ++j) {
    int idx = base + j;
    if (idx < NN) lsum += counts[idx];
  }
  sm[t] = lsum;
  __syncthreads();
  for (int off = 1; off < 1024; off <<= 1) {
    int v = (t >= off) ? sm[t - off] : 0;
    __syncthreads();
    sm[t] += v;
    __syncthreads();
  }
  int run = sm[t] - lsum;  // exclusive prefix for this thread's segment
  for (int j = 0; j < C; ++j) {
    int idx = base + j;
    if (idx < NN) {
      rowptr[idx] = run;
      cursor[idx] = run;
      run += counts[idx];
    }
  }
  if (t == 1023) rowptr[NN] = sm[1023];
}

__global__ __launch_bounds__(256) void k_scatter(const int* __restrict__ ei0,
                                                 const int* __restrict__ ei1,
                                                 int* __restrict__ cursor,
                                                 int* __restrict__ col) {
  int s = blockIdx.y;
  const int* ei = s ? ei1 : ei0;
  int i = blockIdx.x * 256 + threadIdx.x;
  if (i < NE) {
    int dst = ei[NE + i];
    int src = ei[i];
    int pos = atomicAdd(&cursor[s * NN + dst], 1);
    col[(size_t)s * NE + pos] = src;
  }
}

// ---------------------------------------------------------------- aggregation
// One wave per node; lane covers 2 consecutive channels (float2).
template <int W>
__global__ __launch_bounds__(256) void k_agg(const float* __restrict__ h0,
                                             const float* __restrict__ h1,
                                             const int* __restrict__ rowptr_,
                                             const int* __restrict__ col_,
                                             float* __restrict__ agg_) {
  int s = blockIdx.y;
  const float* h = s ? h1 : h0;
  const int* rowptr = rowptr_ + (size_t)s * (NN + 1);
  const int* col = col_ + (size_t)s * NE;
  float* agg = agg_ + (size_t)s * NN * W;
  int wave = threadIdx.x >> 6;
  int lane = threadIdx.x & 63;
  int node = blockIdx.x * 4 + wave;
  if (node >= NN) return;
  int s0 = rowptr[node], s1 = rowptr[node + 1];
  if (W == 128) {
    float2 acc = make_float2(0.f, 0.f);
    const float* hp = h + (lane << 1);
    int j = s0;
    // 4-way unroll: 4 independent loads in flight per trip
    for (; j + 3 < s1; j += 4) {
      int a0 = col[j], a1 = col[j + 1], a2 = col[j + 2], a3 = col[j + 3];
      float2 v0 = *reinterpret_cast<const float2*>(hp + (size_t)a0 * 128);
      float2 v1 = *reinterpret_cast<const float2*>(hp + (size_t)a1 * 128);
      float2 v2 = *reinterpret_cast<const float2*>(hp + (size_t)a2 * 128);
      float2 v3 = *reinterpret_cast<const float2*>(hp + (size_t)a3 * 128);
      acc.x += (v0.x + v1.x) + (v2.x + v3.x);
      acc.y += (v0.y + v1.y) + (v2.y + v3.y);
    }
    for (; j < s1; ++j) {
      int a0 = col[j];
      float2 v0 = *reinterpret_cast<const float2*>(hp + (size_t)a0 * 128);
      acc.x += v0.x;
      acc.y += v0.y;
    }
    *reinterpret_cast<float2*>(agg + (size_t)node * 128 + (lane << 1)) = acc;
  } else {
    // W == 38: lanes 0..18 each own a float2 (19*2 = 38 channels)
    float2 acc = make_float2(0.f, 0.f);
    if (lane < 19) {
      const float* hp = h + (lane << 1);
      int j = s0;
      for (; j + 1 < s1; j += 2) {
        int a0 = col[j], a1 = col[j + 1];
        float2 v0 = *reinterpret_cast<const float2*>(hp + (size_t)a0 * W);
        float2 v1 = *reinterpret_cast<const float2*>(hp + (size_t)a1 * W);
        acc.x += v0.x + v1.x;
        acc.y += v0.y + v1.y;
      }
      if (j < s1) {
        float2 v = *reinterpret_cast<const float2*>(hp + (size_t)col[j] * W);
        acc.x += v.x;
        acc.y += v.y;
      }
      *reinterpret_cast<float2*>(agg + (size_t)node * W + (lane << 1)) = acc;
    }
  }
}

// ---------------------------------------------------------------- GEMM + stats
// Z = A@Wr + X@Ws + b ; also accumulate per-channel sum / sumsq into stats.
// Block: 256 threads, 64 rows x 128 cols, K-chunks of 32. blockIdx.y = side.
__global__ __launch_bounds__(256) void k_gemm(const float* __restrict__ A_, int lda,
                                              const float* __restrict__ X0,
                                              const float* __restrict__ X1, int ldx,
                                              const float* __restrict__ Wr,
                                              const float* __restrict__ Ws,
                                              const float* __restrict__ bias, int K,
                                              float* __restrict__ Z_,
                                              float* __restrict__ stats_) {
  int side = blockIdx.y;
  const float* A = A_ + (size_t)side * NN * lda;
  const float* X = side ? X1 : X0;
  float* Z = Z_ + (size_t)side * NN * HH;
  float* stats = stats_ + (size_t)side * 256;
  __shared__ float sWr[32][128];
  __shared__ float sWs[32][128];
  __shared__ float sA[64][34];
  __shared__ float sX[64][34];
  int t = threadIdx.x;
  int rg = t >> 5;   // 0..7 -> rows rg*8 .. rg*8+7
  int cg = t & 31;   // cols cg*4 .. cg*4+3
  int row0 = blockIdx.x * 64;
  float acc[8][4];
#pragma unroll
  for (int r = 0; r < 8; ++r)
#pragma unroll
    for (int j = 0; j < 4; ++j) acc[r][j] = 0.f;

  for (int kk = 0; kk < K; kk += 32) {
    for (int i = t; i < 1024; i += 256) {
      int k = i >> 5;
      int c = (i & 31) << 2;
      int gk = kk + k;
      float4 vr = make_float4(0, 0, 0, 0), vs = make_float4(0, 0, 0, 0);
      if (gk < K) {
        vr = *reinterpret_cast<const float4*>(Wr + (size_t)gk * HH + c);
        vs = *reinterpret_cast<const float4*>(Ws + (size_t)gk * HH + c);
      }
      *reinterpret_cast<float4*>(&sWr[k][c]) = vr;
      *reinterpret_cast<float4*>(&sWs[k][c]) = vs;
    }
    for (int i = t; i < 1024; i += 256) {
      int r = i >> 4;
      int kc = (i & 15) << 1;
      int grow = row0 + r;
      int gk = kk + kc;
      float2 va = make_float2(0, 0), vx = make_float2(0, 0);
      if (grow < NN && gk < K) {
        va = *reinterpret_cast<const float2*>(A + (size_t)grow * lda + gk);
        vx = *reinterpret_cast<const float2*>(X + (size_t)grow * ldx + gk);
      }
      *reinterpret_cast<float2*>(&sA[r][kc]) = va;
      *reinterpret_cast<float2*>(&sX[r][kc]) = vx;
    }
    __syncthreads();
#pragma unroll
    for (int k = 0; k < 32; k += 2) {
      float4 wr0 = *reinterpret_cast<const float4*>(&sWr[k][cg << 2]);
      float4 ws0 = *reinterpret_cast<const float4*>(&sWs[k][cg << 2]);
      float4 wr1 = *reinterpret_cast<const float4*>(&sWr[k + 1][cg << 2]);
      float4 ws1 = *reinterpret_cast<const float4*>(&sWs[k + 1][cg << 2]);
#pragma unroll
      for (int r = 0; r < 8; ++r) {
        float2 a = *reinterpret_cast<const float2*>(&sA[(rg << 3) + r][k]);
        float2 x = *reinterpret_cast<const float2*>(&sX[(rg << 3) + r][k]);
        acc[r][0] += a.x * wr0.x + x.x * ws0.x + a.y * wr1.x + x.y * ws1.x;
        acc[r][1] += a.x * wr0.y + x.x * ws0.y + a.y * wr1.y + x.y * ws1.y;
        acc[r][2] += a.x * wr0.z + x.x * ws0.z + a.y * wr1.z + x.y * ws1.z;
        acc[r][3] += a.x * wr0.w + x.x * ws0.w + a.y * wr1.w + x.y * ws1.w;
      }
    }
    __syncthreads();
  }
  float4 bv = *reinterpret_cast<const float4*>(bias + (cg << 2));
  float lsum[4] = {0, 0, 0, 0}, lsq[4] = {0, 0, 0, 0};
#pragma unroll
  for (int r = 0; r < 8; ++r) {
    int row = row0 + (rg << 3) + r;
    if (row < NN) {
      float4 z;
      z.x = acc[r][0] + bv.x;
      z.y = acc[r][1] + bv.y;
      z.z = acc[r][2] + bv.z;
      z.w = acc[r][3] + bv.w;
      *reinterpret_cast<float4*>(Z + (size_t)row * HH + (cg << 2)) = z;
      lsum[0] += z.x; lsum[1] += z.y; lsum[2] += z.z; lsum[3] += z.w;
      lsq[0] += z.x * z.x; lsq[1] += z.y * z.y;
      lsq[2] += z.z * z.z; lsq[3] += z.w * z.w;
    }
  }
  __syncthreads();
  float* red = &sWr[0][0];
#pragma unroll
  for (int j = 0; j < 4; ++j) red[rg * HH + (cg << 2) + j] = lsum[j];
  __syncthreads();
  if (t < HH) {
    float sm = 0;
#pragma unroll
    for (int q = 0; q < 8; ++q) sm += red[q * HH + t];
    atomicAdd(&stats[t], sm);
  }
  __syncthreads();
#pragma unroll
  for (int j = 0; j < 4; ++j) red[rg * HH + (cg << 2) + j] = lsq[j];
  __syncthreads();
  if (t < HH) {
    float sm = 0;
#pragma unroll
    for (int q = 0; q < 8; ++q) sm += red[q * HH + t];
    atomicAdd(&stats[HH + t], sm);
  }
}

// ---------------------------------------------------------------- BN
__global__ void k_bnfin(const float* __restrict__ stats_, const float* __restrict__ g,
                        const float* __restrict__ be, float* __restrict__ ss_) {
  int s = blockIdx.x;
  const float* stats = stats_ + (size_t)s * 256;
  float* ss = ss_ + (size_t)s * 256;
  int c = threadIdx.x;
  if (c < HH) {
    float mu = stats[c] * (1.0f / NN);
    float var = stats[HH + c] * (1.0f / NN) - mu * mu;
    float inv = 1.0f / sqrtf(var + 1e-5f);
    float sc = g[c] * inv;
    ss[c] = sc;
    ss[HH + c] = be[c] - mu * sc;
  }
}

__global__ __launch_bounds__(256) void k_bnrelu(float* __restrict__ ZH_,
                                                const float* __restrict__ ss_) {
  int s = blockIdx.y;
  float* ZH = ZH_ + (size_t)s * NN * HH;
  const float* ss = ss_ + (size_t)s * 256;
  size_t i = (size_t)blockIdx.x * 256 + threadIdx.x;  // i indexes float4
  float4 z = *reinterpret_cast<float4*>(ZH + i * 4);
  int c = (int)((i * 4) & 127);
  float4 sc = *reinterpret_cast<const float4*>(ss + c);
  float4 sh = *reinterpret_cast<const float4*>(ss + HH + c);
  z.x = fmaxf(z.x * sc.x + sh.x, 0.f);
  z.y = fmaxf(z.y * sc.y + sh.y, 0.f);
  z.z = fmaxf(z.z * sc.z + sh.z, 0.f);
  z.w = fmaxf(z.w * sc.w + sh.w, 0.f);
  *reinterpret_cast<float4*>(ZH + i * 4) = z;
}

// ---------------------------------------------------------------- gate MLP
__global__ __launch_bounds__(256) void k_gate(const float* __restrict__ Ho_,
                                              const float* __restrict__ Wg1,
                                              const float* __restrict__ bg1,
                                              const float* __restrict__ Wg2,
                                              const float* __restrict__ bg2,
                                              float* __restrict__ gate_) {
  int s = blockIdx.y;
  const float* Ho = Ho_ + (size_t)s * NN * HH;
  float* gate = gate_ + (size_t)s * NN;
  __shared__ float sW[128 * 32];
  int t = threadIdx.x;
  for (int i = t; i < 128 * 32 / 4; i += 256)
    *reinterpret_cast<float4*>(&sW[i * 4]) =
        *reinterpret_cast<const float4*>(Wg1 + i * 4);
  __syncthreads();
  int lane = t & 63, wv = t >> 6;
  int half = lane >> 5, l = lane & 31;
  float w2 = Wg2[l];
  float b2 = bg2[0];
  float b1v = bg1[l];
  for (int it = 0; it < 16; ++it) {
    int node = blockIdx.x * 128 + it * 8 + wv * 2 + half;
    if (node < NN) {
      const float* hr = Ho + (size_t)node * 128;
      float acc = b1v;
      for (int k = 0; k < 128; k += 4) {
        float4 hv = *reinterpret_cast<const float4*>(hr + k);
        acc += hv.x * sW[(k) * 32 + l];
        acc += hv.y * sW[(k + 1) * 32 + l];
        acc += hv.z * sW[(k + 2) * 32 + l];
        acc += hv.w * sW[(k + 3) * 32 + l];
      }
      float v = fmaxf(acc, 0.f) * w2;
#pragma unroll
      for (int off = 16; off > 0; off >>= 1) v += __shfl_down(v, off, 32);
      if (l == 0) gate[node] = fmaxf(v + b2, 0.f);
    }
  }
}

// ---------------------------------------------------------------- pooling
__global__ void k_bounds(const int* __restrict__ batch0,
                         const int* __restrict__ batch1,
                         int* __restrict__ starts, int* __restrict__ ends) {
  int s = blockIdx.x;
  const int* batch = s ? batch1 : batch0;
  int g = threadIdx.x;
  if (g >= NB) return;
  int lo = 0, hi = NN;
  while (lo < hi) { int mid = (lo + hi) >> 1; if (batch[mid] < g) lo = mid + 1; else hi = mid; }
  starts[s * NB + g] = lo;
  lo = 0; hi = NN;
  while (lo < hi) { int mid = (lo + hi) >> 1; if (batch[mid] < g + 1) lo = mid + 1; else hi = mid; }
  ends[s * NB + g] = lo;
}

__global__ __launch_bounds__(256) void k_pool(const float* __restrict__ Ho_,
                                              float* __restrict__ gate_,
                                              const int* __restrict__ starts,
                                              const int* __restrict__ ends,
                                              float* __restrict__ e) {
  int sd = blockIdx.y;
  const float* Ho = Ho_ + (size_t)sd * NN * HH;
  float* gate = gate_ + (size_t)sd * NN;
  __shared__ float red[256];
  int b = blockIdx.x;
  int t = threadIdx.x;
  int s = starts[sd * NB + b], en = ends[sd * NB + b];
  float* eo = e + (size_t)sd * NB * HH + (size_t)b * HH;
  if (en <= s) {
    if (t < 128) eo[t] = 0.f;
    return;
  }
  float m = -3.402823e38f;
  for (int i = s + t; i < en; i += 256) m = fmaxf(m, gate[i]);
  red[t] = m;
  __syncthreads();
  for (int off = 128; off > 0; off >>= 1) {
    if (t < off) red[t] = fmaxf(red[t], red[t + off]);
    __syncthreads();
  }
  float gmax = red[0];
  __syncthreads();
  float ds = 0;
  for (int i = s + t; i < en; i += 256) {
    float eg = expf(gate[i] - gmax);
    gate[i] = eg;
    ds += eg;
  }
  red[t] = ds;
  __syncthreads();
  for (int off = 128; off > 0; off >>= 1) {
    if (t < off) red[t] += red[t + off];
    __syncthreads();
  }
  float inv = 1.0f / red[0];
  __syncthreads();
  int c = t & 127, hhalf = t >> 7;
  float acc = 0;
  for (int i = s + hhalf; i < en; i += 2)
    acc += gate[i] * Ho[(size_t)i * 128 + c];
  red[t] = acc;
  __syncthreads();
  if (t < 128) eo[t] = (red[t] + red[t + 128]) * inv;
}

// ---------------------------------------------------------------- final MLP
__global__ void k_final(const float* __restrict__ e, const float* __restrict__ Wf1,
                        const float* __restrict__ bf1, const float* __restrict__ Wf2,
                        const float* __restrict__ bf2, float* __restrict__ out) {
  int b = blockIdx.x, j = threadIdx.x;  // 64 threads
  float acc = bf1[j];
  const float* e1 = e + (size_t)b * 128;
  const float* e2 = e + (size_t)NB * 128 + (size_t)b * 128;
  for (int k = 0; k < 128; ++k) {
    float d = fabsf(e1[k] - e2[k]);
    acc += d * Wf1[k * 64 + j];
  }
  float v = fmaxf(acc, 0.f) * Wf2[j];
#pragma unroll
  for (int off = 32; off > 0; off >>= 1) v += __shfl_down(v, off, 64);
  if (j == 0) out[b] = v + bf2[0];
}

// ---------------------------------------------------------------- launch
extern "C" void kernel_launch(void* const* d_in, const int* in_sizes, int n_in,
                              void* d_out, int out_size, void* d_ws, size_t ws_size,
                              hipStream_t stream) {
  const float* x0 = (const float*)d_in[0];
  const float* x1 = (const float*)d_in[1];
  const int* ei0 = (const int*)d_in[2];
  const int* ei1 = (const int*)d_in[3];
  const int* batch0 = (const int*)d_in[4];
  const int* batch1 = (const int*)d_in[5];
  const float* W1r = (const float*)d_in[6];
  const float* W1s = (const float*)d_in[7];
  const float* b1 = (const float*)d_in[8];
  const float* g1 = (const float*)d_in[9];
  const float* be1 = (const float*)d_in[10];
  const float* W2r = (const float*)d_in[11];
  const float* W2s = (const float*)d_in[12];
  const float* b2 = (const float*)d_in[13];
  const float* g2 = (const float*)d_in[14];
  const float* be2 = (const float*)d_in[15];
  const float* W3r = (const float*)d_in[16];
  const float* W3s = (const float*)d_in[17];
  const float* b3 = (const float*)d_in[18];
  const float* g3 = (const float*)d_in[19];
  const float* be3 = (const float*)d_in[20];
  const float* Wg1 = (const float*)d_in[21];
  const float* bg1 = (const float*)d_in[22];
  const float* Wg2 = (const float*)d_in[23];
  const float* bg2 = (const float*)d_in[24];
  const float* Wf1 = (const float*)d_in[25];
  const float* bf1 = (const float*)d_in[26];
  const float* Wf2 = (const float*)d_in[27];
  const float* bf2 = (const float*)d_in[28];

  char* p = (char*)d_ws;
  auto alloc = [&](size_t bytes) {
    void* r = (void*)p;
    p += (bytes + 255) & ~(size_t)255;
    return r;
  };
  int* counts = (int*)alloc((size_t)2 * NN * 4);
  int* rowptr = (int*)alloc((size_t)2 * (NN + 1) * 4);
  int* cursor = (int*)alloc((size_t)2 * NN * 4);
  int* col = (int*)alloc((size_t)2 * NE * 4);
  int* starts = (int*)alloc(2 * NB * 4);
  int* ends = (int*)alloc(2 * NB * 4);
  float* stats = (float*)alloc(2 * 256 * 4);
  float* ss = (float*)alloc(2 * 256 * 4);
  float* gate = (float*)alloc((size_t)2 * NN * 4);
  float* ebuf = (float*)alloc((size_t)2 * NB * HH * 4);
  float* bufA = (float*)alloc((size_t)2 * NN * HH * 4);  // agg output (38- or 128-wide)
  float* bufB = (float*)alloc((size_t)2 * NN * HH * 4);  // h1 / h3
  float* bufC = (float*)alloc((size_t)2 * NN * HH * 4);  // h2

  // ---- CSR build (both sides)
  hipMemsetAsync(counts, 0, (size_t)2 * NN * 4, stream);
  k_hist<<<dim3((NE + 255) / 256, 2), 256, 0, stream>>>(ei0, ei1, counts);
  k_scan<<<2, 1024, 0, stream>>>(counts, rowptr, cursor);
  k_scatter<<<dim3((NE + 255) / 256, 2), 256, 0, stream>>>(ei0, ei1, cursor, col);

  // ---- layer 1: F=38 -> 128   (agg stride 38)
  k_agg<38><<<dim3(15000, 2), 256, 0, stream>>>(x0, x1, rowptr, col, bufA);
  hipMemsetAsync(stats, 0, 2 * 256 * 4, stream);
  k_gemm<<<dim3(938, 2), 256, 0, stream>>>(bufA, FIN, x0, x1, FIN, W1r, W1s, b1, FIN,
                                           bufB, stats);
  k_bnfin<<<2, 128, 0, stream>>>(stats, g1, be1, ss);
  k_bnrelu<<<dim3(7500, 2), 256, 0, stream>>>(bufB, ss);

  // ---- layer 2: 128 -> 128
  k_agg<128><<<dim3(15000, 2), 256, 0, stream>>>(bufB, bufB + (size_t)NN * HH,
                                                 rowptr, col, bufA);
  hipMemsetAsync(stats, 0, 2 * 256 * 4, stream);
  k_gemm<<<dim3(938, 2), 256, 0, stream>>>(bufA, HH, bufB, bufB + (size_t)NN * HH, HH,
                                           W2r, W2s, b2, HH, bufC, stats);
  k_bnfin<<<2, 128, 0, stream>>>(stats, g2, be2, ss);
  k_bnrelu<<<dim3(7500, 2), 256, 0, stream>>>(bufC, ss);

  // ---- layer 3: 128 -> 128
  k_agg<128><<<dim3(15000, 2), 256, 0, stream>>>(bufC, bufC + (size_t)NN * HH,
                                                 rowptr, col, bufA);
  hipMemsetAsync(stats, 0, 2 * 256 * 4, stream);
  k_gemm<<<dim3(938, 2), 256, 0, stream>>>(bufA, HH, bufC, bufC + (size_t)NN * HH, HH,
                                           W3r, W3s, b3, HH, bufB, stats);
  k_bnfin<<<2, 128, 0, stream>>>(stats, g3, be3, ss);
  k_bnrelu<<<dim3(7500, 2), 256, 0, stream>>>(bufB, ss);

  // ---- gate + attention pool (both sides)
  k_gate<<<dim3(469, 2), 256, 0, stream>>>(bufB, Wg1, bg1, Wg2, bg2, gate);
  k_bounds<<<2, 32, 0, stream>>>(batch0, batch1, starts, ends);
  k_pool<<<dim3(NB, 2), 256, 0, stream>>>(bufB, gate, starts, ends, ebuf);

  k_final<<<NB, 64, 0, stream>>>(ebuf, Wf1, bf1, Wf2, bf2, (float*)d_out);
}

// Round 9
// 1582.696 us; speedup vs baseline: 1.2183x; 1.2183x over previous
//
#include <hip/hip_runtime.h>
#include <cstdint>
#include <cstddef>

#define NN 60000
#define NE 960000
#define NB 32
#define FIN 38
#define HH 128

typedef short bf16x8 __attribute__((ext_vector_type(8)));
typedef float f32x4 __attribute__((ext_vector_type(4)));

__device__ __forceinline__ unsigned short f2bf(float x) {
  unsigned u = __builtin_bit_cast(unsigned, x);
  u = u + 0x7fffu + ((u >> 16) & 1u);
  return (unsigned short)(u >> 16);
}
__device__ __forceinline__ float bf2f(unsigned short h) {
  unsigned u = ((unsigned)h) << 16;
  return __builtin_bit_cast(float, u);
}

// ---------------------------------------------------------------- CSR build
__global__ __launch_bounds__(256) void k_hist(const int* __restrict__ ei0,
                                              const int* __restrict__ ei1,
                                              int* __restrict__ counts) {
  int s = blockIdx.y;
  const int* ei = s ? ei1 : ei0;
  int i = blockIdx.x * 256 + threadIdx.x;
  if (i < NE) atomicAdd(&counts[s * NN + ei[NE + i]], 1);
}

__global__ __launch_bounds__(1024) void k_scan(const int* __restrict__ counts_,
                                               int* __restrict__ rowptr_,
                                               int* __restrict__ cursor_) {
  int s = blockIdx.x;
  const int* counts = counts_ + (size_t)s * NN;
  int* rowptr = rowptr_ + (size_t)s * (NN + 1);
  int* cursor = cursor_ + (size_t)s * NN;
  __shared__ int sm[1024];
  const int C = 59;  // 1024*59 = 60416 >= NN
  int t = threadIdx.x;
  int base = t * C;
  int lsum = 0;
  for (int j = 0; j < C; ++j) {
    int idx = base + j;
    if (idx < NN) lsum += counts[idx];
  }
  sm[t] = lsum;
  __syncthreads();
  for (int off = 1; off < 1024; off <<= 1) {
    int v = (t >= off) ? sm[t - off] : 0;
    __syncthreads();
    sm[t] += v;
    __syncthreads();
  }
  int run = sm[t] - lsum;
  for (int j = 0; j < C; ++j) {
    int idx = base + j;
    if (idx < NN) {
      rowptr[idx] = run;
      cursor[idx] = run;
      run += counts[idx];
    }
  }
  if (t == 1023) rowptr[NN] = sm[1023];
}

__global__ __launch_bounds__(256) void k_scatter(const int* __restrict__ ei0,
                                                 const int* __restrict__ ei1,
                                                 int* __restrict__ cursor,
                                                 int* __restrict__ col) {
  int s = blockIdx.y;
  const int* ei = s ? ei1 : ei0;
  int i = blockIdx.x * 256 + threadIdx.x;
  if (i < NE) {
    int dst = ei[NE + i];
    int src = ei[i];
    int pos = atomicAdd(&cursor[s * NN + dst], 1);
    col[(size_t)s * NE + pos] = src;
  }
}

// ---------------------------------------------------------------- aggregation
template <int W>
__global__ __launch_bounds__(256) void k_agg(const float* __restrict__ h0,
                                             const float* __restrict__ h1,
                                             const int* __restrict__ rowptr_,
                                             const int* __restrict__ col_,
                                             float* __restrict__ agg_) {
  int s = blockIdx.y;
  const float* h = s ? h1 : h0;
  const int* rowptr = rowptr_ + (size_t)s * (NN + 1);
  const int* col = col_ + (size_t)s * NE;
  float* agg = agg_ + (size_t)s * NN * W;
  int wave = threadIdx.x >> 6;
  int lane = threadIdx.x & 63;
  int node = blockIdx.x * 4 + wave;
  if (node >= NN) return;
  int s0 = rowptr[node], s1 = rowptr[node + 1];
  if (W == 128) {
    float2 acc = make_float2(0.f, 0.f);
    const float* hp = h + (lane << 1);
    int j = s0;
    for (; j + 3 < s1; j += 4) {
      int a0 = col[j], a1 = col[j + 1], a2 = col[j + 2], a3 = col[j + 3];
      float2 v0 = *reinterpret_cast<const float2*>(hp + (size_t)a0 * 128);
      float2 v1 = *reinterpret_cast<const float2*>(hp + (size_t)a1 * 128);
      float2 v2 = *reinterpret_cast<const float2*>(hp + (size_t)a2 * 128);
      float2 v3 = *reinterpret_cast<const float2*>(hp + (size_t)a3 * 128);
      acc.x += (v0.x + v1.x) + (v2.x + v3.x);
      acc.y += (v0.y + v1.y) + (v2.y + v3.y);
    }
    for (; j < s1; ++j) {
      int a0 = col[j];
      float2 v0 = *reinterpret_cast<const float2*>(hp + (size_t)a0 * 128);
      acc.x += v0.x;
      acc.y += v0.y;
    }
    *reinterpret_cast<float2*>(agg + (size_t)node * 128 + (lane << 1)) = acc;
  } else {
    float2 acc = make_float2(0.f, 0.f);
    if (lane < 19) {
      const float* hp = h + (lane << 1);
      int j = s0;
      for (; j + 1 < s1; j += 2) {
        int a0 = col[j], a1 = col[j + 1];
        float2 v0 = *reinterpret_cast<const float2*>(hp + (size_t)a0 * W);
        float2 v1 = *reinterpret_cast<const float2*>(hp + (size_t)a1 * W);
        acc.x += v0.x + v1.x;
        acc.y += v0.y + v1.y;
      }
      if (j < s1) {
        float2 v = *reinterpret_cast<const float2*>(hp + (size_t)col[j] * W);
        acc.x += v.x;
        acc.y += v.y;
      }
      *reinterpret_cast<float2*>(agg + (size_t)node * W + (lane << 1)) = acc;
    }
  }
}

// ---------------------------------------------------------------- MFMA GEMM
// Z = A@Wr + X@Ws + b via split-bf16 (fp32 = hi + lo): 3 MFMAs per product
// (hh + hl + lh), fp32 accumulate. Also per-channel sum/sumsq into stats.
// Block: 256 thr = 4 waves; tile 64 rows x 128 cols; wave = 32r x 64c
// (2x4 tiles of mfma_f32_16x16x32_bf16). K staged in 32-chunks, LDS
// XOR-swizzled ((idx&7)<<4) so frag b128 reads are <=2-way bank aliased.
template <bool VEC>
__global__ __launch_bounds__(256) void k_gemm_mfma(
    const float* __restrict__ A_, int lda, const float* __restrict__ X0,
    const float* __restrict__ X1, int ldx, const float* __restrict__ Wr,
    const float* __restrict__ Ws, const float* __restrict__ bias, int K,
    float* __restrict__ Z_, float* __restrict__ stats_) {
  int side = blockIdx.y;
  const float* A = A_ + (size_t)side * NN * lda;
  const float* X = side ? X1 : X0;
  float* Z = Z_ + (size_t)side * NN * HH;
  float* stats = stats_ + (size_t)side * 256;

  __shared__ __align__(16) unsigned char sAh[64 * 64];
  __shared__ __align__(16) unsigned char sAl[64 * 64];
  __shared__ __align__(16) unsigned char sXh[64 * 64];
  __shared__ __align__(16) unsigned char sXl[64 * 64];
  __shared__ __align__(16) unsigned char sBh[2][128 * 64];  // [0]=Wr [1]=Ws
  __shared__ __align__(16) unsigned char sBl[2][128 * 64];

  int t = threadIdx.x;
  int l = t & 63;
  int wid = t >> 6;
  int wr = wid >> 1, wc = wid & 1;
  int row0 = blockIdx.x * 64;

  f32x4 acc[2][4];
#pragma unroll
  for (int rt = 0; rt < 2; ++rt)
#pragma unroll
    for (int ct = 0; ct < 4; ++ct) acc[rt][ct] = (f32x4)(0.f);

  int nK = (K + 31) >> 5;
  for (int ks = 0; ks < nK; ++ks) {
    // ---- stage A/X tile: 64 rows x 32 k, split hi/lo bf16
    {
      int r = t >> 2;
      int kc = (t & 3) << 3;  // k-span base (8 k per thread)
      int grow = row0 + r;
      float av[8], xv[8];
      if (VEC) {
        float4 a0 = make_float4(0, 0, 0, 0), a1 = a0, x0 = a0, x1 = a0;
        if (grow < NN) {
          const float* pa = A + (size_t)grow * lda + (ks << 5) + kc;
          const float* px = X + (size_t)grow * ldx + (ks << 5) + kc;
          a0 = *reinterpret_cast<const float4*>(pa);
          a1 = *reinterpret_cast<const float4*>(pa + 4);
          x0 = *reinterpret_cast<const float4*>(px);
          x1 = *reinterpret_cast<const float4*>(px + 4);
        }
        av[0] = a0.x; av[1] = a0.y; av[2] = a0.z; av[3] = a0.w;
        av[4] = a1.x; av[5] = a1.y; av[6] = a1.z; av[7] = a1.w;
        xv[0] = x0.x; xv[1] = x0.y; xv[2] = x0.z; xv[3] = x0.w;
        xv[4] = x1.x; xv[5] = x1.y; xv[6] = x1.z; xv[7] = x1.w;
      } else {
#pragma unroll
        for (int e = 0; e < 8; ++e) {
          int gk = (ks << 5) + kc + e;
          bool ok = (grow < NN) && (gk < K);
          av[e] = ok ? A[(size_t)grow * lda + gk] : 0.f;
          xv[e] = ok ? X[(size_t)grow * ldx + gk] : 0.f;
        }
      }
      bf16x8 ah, al, xh, xl;
#pragma unroll
      for (int e = 0; e < 8; ++e) {
        unsigned short h = f2bf(av[e]);
        ah[e] = (short)h;
        al[e] = (short)f2bf(av[e] - bf2f(h));
        h = f2bf(xv[e]);
        xh[e] = (short)h;
        xl[e] = (short)f2bf(xv[e] - bf2f(h));
      }
      int off = ((r << 6) + (kc << 1)) ^ ((r & 7) << 4);
      *reinterpret_cast<bf16x8*>(sAh + off) = ah;
      *reinterpret_cast<bf16x8*>(sAl + off) = al;
      *reinterpret_cast<bf16x8*>(sXh + off) = xh;
      *reinterpret_cast<bf16x8*>(sXl + off) = xl;
    }
    // ---- stage weights: 32 k x 128 cols, transposed to [col][k], split
    {
      int kq = t >> 5;         // k-quad 0..7
      int c0 = (t & 31) << 2;  // col base
      float wf[2][4][4];       // [mat][krow][col]
#pragma unroll
      for (int kk = 0; kk < 4; ++kk) {
        int gk = (ks << 5) + (kq << 2) + kk;
        float4 vr = make_float4(0, 0, 0, 0), vs = vr;
        if (gk < K) {
          vr = *reinterpret_cast<const float4*>(Wr + (size_t)gk * HH + c0);
          vs = *reinterpret_cast<const float4*>(Ws + (size_t)gk * HH + c0);
        }
        wf[0][kk][0] = vr.x; wf[0][kk][1] = vr.y; wf[0][kk][2] = vr.z; wf[0][kk][3] = vr.w;
        wf[1][kk][0] = vs.x; wf[1][kk][1] = vs.y; wf[1][kk][2] = vs.z; wf[1][kk][3] = vs.w;
      }
#pragma unroll
      for (int m = 0; m < 2; ++m) {
#pragma unroll
        for (int j = 0; j < 4; ++j) {
          int c = c0 + j;
          unsigned h0 = f2bf(wf[m][0][j]), h1 = f2bf(wf[m][1][j]);
          unsigned h2 = f2bf(wf[m][2][j]), h3 = f2bf(wf[m][3][j]);
          unsigned l0 = f2bf(wf[m][0][j] - bf2f((unsigned short)h0));
          unsigned l1 = f2bf(wf[m][1][j] - bf2f((unsigned short)h1));
          unsigned l2 = f2bf(wf[m][2][j] - bf2f((unsigned short)h2));
          unsigned l3 = f2bf(wf[m][3][j] - bf2f((unsigned short)h3));
          uint2 hv = make_uint2(h0 | (h1 << 16), h2 | (h3 << 16));
          uint2 lv = make_uint2(l0 | (l1 << 16), l2 | (l3 << 16));
          int off = ((c << 6) + (kq << 3)) ^ ((c & 7) << 4);
          *reinterpret_cast<uint2*>(sBh[m] + off) = hv;
          *reinterpret_cast<uint2*>(sBl[m] + off) = lv;
        }
      }
    }
    __syncthreads();
    // ---- MFMA phase
    bf16x8 fah[2], fal[2], fxh[2], fxl[2];
    int ko = (l >> 4) << 4;  // byte offset of this lane's 8-k span
#pragma unroll
    for (int rt = 0; rt < 2; ++rt) {
      int rr = (wr << 5) + (rt << 4) + (l & 15);
      int off = ((rr << 6) + ko) ^ ((rr & 7) << 4);
      fah[rt] = *reinterpret_cast<const bf16x8*>(sAh + off);
      fal[rt] = *reinterpret_cast<const bf16x8*>(sAl + off);
      fxh[rt] = *reinterpret_cast<const bf16x8*>(sXh + off);
      fxl[rt] = *reinterpret_cast<const bf16x8*>(sXl + off);
    }
#pragma unroll
    for (int ct = 0; ct < 4; ++ct) {
      int cc = (wc << 6) + (ct << 4) + (l & 15);
      int off = ((cc << 6) + ko) ^ ((cc & 7) << 4);
      bf16x8 brh = *reinterpret_cast<const bf16x8*>(sBh[0] + off);
      bf16x8 brl = *reinterpret_cast<const bf16x8*>(sBl[0] + off);
      bf16x8 bsh = *reinterpret_cast<const bf16x8*>(sBh[1] + off);
      bf16x8 bsl = *reinterpret_cast<const bf16x8*>(sBl[1] + off);
#pragma unroll
      for (int rt = 0; rt < 2; ++rt) {
        f32x4 c = acc[rt][ct];
        c = __builtin_amdgcn_mfma_f32_16x16x32_bf16(fah[rt], brh, c, 0, 0, 0);
        c = __builtin_amdgcn_mfma_f32_16x16x32_bf16(fah[rt], brl, c, 0, 0, 0);
        c = __builtin_amdgcn_mfma_f32_16x16x32_bf16(fal[rt], brh, c, 0, 0, 0);
        c = __builtin_amdgcn_mfma_f32_16x16x32_bf16(fxh[rt], bsh, c, 0, 0, 0);
        c = __builtin_amdgcn_mfma_f32_16x16x32_bf16(fxh[rt], bsl, c, 0, 0, 0);
        c = __builtin_amdgcn_mfma_f32_16x16x32_bf16(fxl[rt], bsh, c, 0, 0, 0);
        acc[rt][ct] = c;
      }
    }
    __syncthreads();
  }

  // ---- epilogue: bias, store Z, per-channel stats
  float ps[4] = {0, 0, 0, 0}, pq[4] = {0, 0, 0, 0};
#pragma unroll
  for (int ct = 0; ct < 4; ++ct) {
    int col = (wc << 6) + (ct << 4) + (l & 15);
    float b = bias[col];
#pragma unroll
    for (int rt = 0; rt < 2; ++rt) {
      int rbase = row0 + (wr << 5) + (rt << 4) + ((l >> 4) << 2);
      f32x4 v = acc[rt][ct];
#pragma unroll
      for (int rg = 0; rg < 4; ++rg) {
        int row = rbase + rg;
        if (row < NN) {
          float z = v[rg] + b;
          Z[(size_t)row * HH + col] = z;
          ps[ct] += z;
          pq[ct] += z * z;
        }
      }
    }
  }
#pragma unroll
  for (int ct = 0; ct < 4; ++ct) {
    ps[ct] += __shfl_xor(ps[ct], 16, 64);
    ps[ct] += __shfl_xor(ps[ct], 32, 64);
    pq[ct] += __shfl_xor(pq[ct], 16, 64);
    pq[ct] += __shfl_xor(pq[ct], 32, 64);
  }
  if (l < 16) {
#pragma unroll
    for (int ct = 0; ct < 4; ++ct) {
      int col = (wc << 6) + (ct << 4) + l;
      atomicAdd(&stats[col], ps[ct]);
      atomicAdd(&stats[HH + col], pq[ct]);
    }
  }
}

// ---------------------------------------------------------------- BN
__global__ void k_bnfin(const float* __restrict__ stats_, const float* __restrict__ g,
                        const float* __restrict__ be, float* __restrict__ ss_) {
  int s = blockIdx.x;
  const float* stats = stats_ + (size_t)s * 256;
  float* ss = ss_ + (size_t)s * 256;
  int c = threadIdx.x;
  if (c < HH) {
    float mu = stats[c] * (1.0f / NN);
    float var = stats[HH + c] * (1.0f / NN) - mu * mu;
    float inv = 1.0f / sqrtf(var + 1e-5f);
    float sc = g[c] * inv;
    ss[c] = sc;
    ss[HH + c] = be[c] - mu * sc;
  }
}

__global__ __launch_bounds__(256) void k_bnrelu(float* __restrict__ ZH_,
                                                const float* __restrict__ ss_) {
  int s = blockIdx.y;
  float* ZH = ZH_ + (size_t)s * NN * HH;
  const float* ss = ss_ + (size_t)s * 256;
  size_t i = (size_t)blockIdx.x * 256 + threadIdx.x;
  float4 z = *reinterpret_cast<float4*>(ZH + i * 4);
  int c = (int)((i * 4) & 127);
  float4 sc = *reinterpret_cast<const float4*>(ss + c);
  float4 sh = *reinterpret_cast<const float4*>(ss + HH + c);
  z.x = fmaxf(z.x * sc.x + sh.x, 0.f);
  z.y = fmaxf(z.y * sc.y + sh.y, 0.f);
  z.z = fmaxf(z.z * sc.z + sh.z, 0.f);
  z.w = fmaxf(z.w * sc.w + sh.w, 0.f);
  *reinterpret_cast<float4*>(ZH + i * 4) = z;
}

// ---------------------------------------------------------------- gate MLP
__global__ __launch_bounds__(256) void k_gate(const float* __restrict__ Ho_,
                                              const float* __restrict__ Wg1,
                                              const float* __restrict__ bg1,
                                              const float* __restrict__ Wg2,
                                              const float* __restrict__ bg2,
                                              float* __restrict__ gate_) {
  int s = blockIdx.y;
  const float* Ho = Ho_ + (size_t)s * NN * HH;
  float* gate = gate_ + (size_t)s * NN;
  __shared__ float sW[128 * 32];
  int t = threadIdx.x;
  for (int i = t; i < 128 * 32 / 4; i += 256)
    *reinterpret_cast<float4*>(&sW[i * 4]) =
        *reinterpret_cast<const float4*>(Wg1 + i * 4);
  __syncthreads();
  int lane = t & 63, wv = t >> 6;
  int half = lane >> 5, l = lane & 31;
  float w2 = Wg2[l];
  float b2 = bg2[0];
  float b1v = bg1[l];
  for (int it = 0; it < 16; ++it) {
    int node = blockIdx.x * 128 + it * 8 + wv * 2 + half;
    if (node < NN) {
      const float* hr = Ho + (size_t)node * 128;
      float acc = b1v;
      for (int k = 0; k < 128; k += 4) {
        float4 hv = *reinterpret_cast<const float4*>(hr + k);
        acc += hv.x * sW[(k) * 32 + l];
        acc += hv.y * sW[(k + 1) * 32 + l];
        acc += hv.z * sW[(k + 2) * 32 + l];
        acc += hv.w * sW[(k + 3) * 32 + l];
      }
      float v = fmaxf(acc, 0.f) * w2;
#pragma unroll
      for (int off = 16; off > 0; off >>= 1) v += __shfl_down(v, off, 32);
      if (l == 0) gate[node] = fmaxf(v + b2, 0.f);
    }
  }
}

// ---------------------------------------------------------------- pooling
__global__ void k_bounds(const int* __restrict__ batch0,
                         const int* __restrict__ batch1,
                         int* __restrict__ starts, int* __restrict__ ends) {
  int s = blockIdx.x;
  const int* batch = s ? batch1 : batch0;
  int g = threadIdx.x;
  if (g >= NB) return;
  int lo = 0, hi = NN;
  while (lo < hi) { int mid = (lo + hi) >> 1; if (batch[mid] < g) lo = mid + 1; else hi = mid; }
  starts[s * NB + g] = lo;
  lo = 0; hi = NN;
  while (lo < hi) { int mid = (lo + hi) >> 1; if (batch[mid] < g + 1) lo = mid + 1; else hi = mid; }
  ends[s * NB + g] = lo;
}

__global__ __launch_bounds__(256) void k_pool(const float* __restrict__ Ho_,
                                              float* __restrict__ gate_,
                                              const int* __restrict__ starts,
                                              const int* __restrict__ ends,
                                              float* __restrict__ e) {
  int sd = blockIdx.y;
  const float* Ho = Ho_ + (size_t)sd * NN * HH;
  float* gate = gate_ + (size_t)sd * NN;
  __shared__ float red[256];
  int b = blockIdx.x;
  int t = threadIdx.x;
  int s = starts[sd * NB + b], en = ends[sd * NB + b];
  float* eo = e + (size_t)sd * NB * HH + (size_t)b * HH;
  if (en <= s) {
    if (t < 128) eo[t] = 0.f;
    return;
  }
  float m = -3.402823e38f;
  for (int i = s + t; i < en; i += 256) m = fmaxf(m, gate[i]);
  red[t] = m;
  __syncthreads();
  for (int off = 128; off > 0; off >>= 1) {
    if (t < off) red[t] = fmaxf(red[t], red[t + off]);
    __syncthreads();
  }
  float gmax = red[0];
  __syncthreads();
  float ds = 0;
  for (int i = s + t; i < en; i += 256) {
    float eg = expf(gate[i] - gmax);
    gate[i] = eg;
    ds += eg;
  }
  red[t] = ds;
  __syncthreads();
  for (int off = 128; off > 0; off >>= 1) {
    if (t < off) red[t] += red[t + off];
    __syncthreads();
  }
  float inv = 1.0f / red[0];
  __syncthreads();
  int c = t & 127, hhalf = t >> 7;
  float acc = 0;
  for (int i = s + hhalf; i < en; i += 2)
    acc += gate[i] * Ho[(size_t)i * 128 + c];
  red[t] = acc;
  __syncthreads();
  if (t < 128) eo[t] = (red[t] + red[t + 128]) * inv;
}

// ---------------------------------------------------------------- final MLP
__global__ void k_final(const float* __restrict__ e, const float* __restrict__ Wf1,
                        const float* __restrict__ bf1, const float* __restrict__ Wf2,
                        const float* __restrict__ bf2, float* __restrict__ out) {
  int b = blockIdx.x, j = threadIdx.x;  // 64 threads
  float acc = bf1[j];
  const float* e1 = e + (size_t)b * 128;
  const float* e2 = e + (size_t)NB * 128 + (size_t)b * 128;
  for (int k = 0; k < 128; ++k) {
    float d = fabsf(e1[k] - e2[k]);
    acc += d * Wf1[k * 64 + j];
  }
  float v = fmaxf(acc, 0.f) * Wf2[j];
#pragma unroll
  for (int off = 32; off > 0; off >>= 1) v += __shfl_down(v, off, 64);
  if (j == 0) out[b] = v + bf2[0];
}

// ---------------------------------------------------------------- launch
extern "C" void kernel_launch(void* const* d_in, const int* in_sizes, int n_in,
                              void* d_out, int out_size, void* d_ws, size_t ws_size,
                              hipStream_t stream) {
  const float* x0 = (const float*)d_in[0];
  const float* x1 = (const float*)d_in[1];
  const int* ei0 = (const int*)d_in[2];
  const int* ei1 = (const int*)d_in[3];
  const int* batch0 = (const int*)d_in[4];
  const int* batch1 = (const int*)d_in[5];
  const float* W1r = (const float*)d_in[6];
  const float* W1s = (const float*)d_in[7];
  const float* b1 = (const float*)d_in[8];
  const float* g1 = (const float*)d_in[9];
  const float* be1 = (const float*)d_in[10];
  const float* W2r = (const float*)d_in[11];
  const float* W2s = (const float*)d_in[12];
  const float* b2 = (const float*)d_in[13];
  const float* g2 = (const float*)d_in[14];
  const float* be2 = (const float*)d_in[15];
  const float* W3r = (const float*)d_in[16];
  const float* W3s = (const float*)d_in[17];
  const float* b3 = (const float*)d_in[18];
  const float* g3 = (const float*)d_in[19];
  const float* be3 = (const float*)d_in[20];
  const float* Wg1 = (const float*)d_in[21];
  const float* bg1 = (const float*)d_in[22];
  const float* Wg2 = (const float*)d_in[23];
  const float* bg2 = (const float*)d_in[24];
  const float* Wf1 = (const float*)d_in[25];
  const float* bf1 = (const float*)d_in[26];
  const float* Wf2 = (const float*)d_in[27];
  const float* bf2 = (const float*)d_in[28];

  char* p = (char*)d_ws;
  auto alloc = [&](size_t bytes) {
    void* r = (void*)p;
    p += (bytes + 255) & ~(size_t)255;
    return r;
  };
  int* counts = (int*)alloc((size_t)2 * NN * 4);
  int* rowptr = (int*)alloc((size_t)2 * (NN + 1) * 4);
  int* cursor = (int*)alloc((size_t)2 * NN * 4);
  int* col = (int*)alloc((size_t)2 * NE * 4);
  int* starts = (int*)alloc(2 * NB * 4);
  int* ends = (int*)alloc(2 * NB * 4);
  float* stats = (float*)alloc(2 * 256 * 4);
  float* ss = (float*)alloc(2 * 256 * 4);
  float* gate = (float*)alloc((size_t)2 * NN * 4);
  float* ebuf = (float*)alloc((size_t)2 * NB * HH * 4);
  float* bufA = (float*)alloc((size_t)2 * NN * HH * 4);
  float* bufB = (float*)alloc((size_t)2 * NN * HH * 4);
  float* bufC = (float*)alloc((size_t)2 * NN * HH * 4);

  // ---- CSR build (both sides)
  hipMemsetAsync(counts, 0, (size_t)2 * NN * 4, stream);
  k_hist<<<dim3((NE + 255) / 256, 2), 256, 0, stream>>>(ei0, ei1, counts);
  k_scan<<<2, 1024, 0, stream>>>(counts, rowptr, cursor);
  k_scatter<<<dim3((NE + 255) / 256, 2), 256, 0, stream>>>(ei0, ei1, cursor, col);

  // ---- layer 1: F=38 -> 128
  k_agg<38><<<dim3(15000, 2), 256, 0, stream>>>(x0, x1, rowptr, col, bufA);
  hipMemsetAsync(stats, 0, 2 * 256 * 4, stream);
  k_gemm_mfma<false><<<dim3(938, 2), 256, 0, stream>>>(
      bufA, FIN, x0, x1, FIN, W1r, W1s, b1, FIN, bufB, stats);
  k_bnfin<<<2, 128, 0, stream>>>(stats, g1, be1, ss);
  k_bnrelu<<<dim3(7500, 2), 256, 0, stream>>>(bufB, ss);

  // ---- layer 2: 128 -> 128
  k_agg<128><<<dim3(15000, 2), 256, 0, stream>>>(bufB, bufB + (size_t)NN * HH,
                                                 rowptr, col, bufA);
  hipMemsetAsync(stats, 0, 2 * 256 * 4, stream);
  k_gemm_mfma<true><<<dim3(938, 2), 256, 0, stream>>>(
      bufA, HH, bufB, bufB + (size_t)NN * HH, HH, W2r, W2s, b2, HH, bufC, stats);
  k_bnfin<<<2, 128, 0, stream>>>(stats, g2, be2, ss);
  k_bnrelu<<<dim3(7500, 2), 256, 0, stream>>>(bufC, ss);

  // ---- layer 3: 128 -> 128
  k_agg<128><<<dim3(15000, 2), 256, 0, stream>>>(bufC, bufC + (size_t)NN * HH,
                                                 rowptr, col, bufA);
  hipMemsetAsync(stats, 0, 2 * 256 * 4, stream);
  k_gemm_mfma<true><<<dim3(938, 2), 256, 0, stream>>>(
      bufA, HH, bufC, bufC + (size_t)NN * HH, HH, W3r, W3s, b3, HH, bufB, stats);
  k_bnfin<<<2, 128, 0, stream>>>(stats, g3, be3, ss);
  k_bnrelu<<<dim3(7500, 2), 256, 0, stream>>>(bufB, ss);

  // ---- gate + attention pool (both sides)
  k_gate<<<dim3(469, 2), 256, 0, stream>>>(bufB, Wg1, bg1, Wg2, bg2, gate);
  k_bounds<<<2, 32, 0, stream>>>(batch0, batch1, starts, ends);
  k_pool<<<dim3(NB, 2), 256, 0, stream>>>(bufB, gate, starts, ends, ebuf);

  k_final<<<NB, 64, 0, stream>>>(ebuf, Wf1, bf1, Wf2, bf2, (float*)d_out);
}

// Round 10
// 1389.384 us; speedup vs baseline: 1.3878x; 1.1391x over previous
//
#include <hip/hip_runtime.h>
#include <cstdint>
#include <cstddef>

#define NN 60000
#define NE 960000
#define NB 32
#define FIN 38
#define HH 128

typedef short bf16x8 __attribute__((ext_vector_type(8)));
typedef float f32x4 __attribute__((ext_vector_type(4)));

__device__ __forceinline__ unsigned short f2bf(float x) {
  unsigned u = __builtin_bit_cast(unsigned, x);
  u = u + 0x7fffu + ((u >> 16) & 1u);
  return (unsigned short)(u >> 16);
}
__device__ __forceinline__ float bf2f(unsigned short h) {
  unsigned u = ((unsigned)h) << 16;
  return __builtin_bit_cast(float, u);
}

// ---------------------------------------------------------------- CSR build
__global__ __launch_bounds__(256) void k_hist(const int* __restrict__ ei0,
                                              const int* __restrict__ ei1,
                                              int* __restrict__ counts) {
  int s = blockIdx.y;
  const int* ei = s ? ei1 : ei0;
  int i = blockIdx.x * 256 + threadIdx.x;
  if (i < NE) atomicAdd(&counts[s * NN + ei[NE + i]], 1);
}

__global__ __launch_bounds__(1024) void k_scan(const int* __restrict__ counts_,
                                               int* __restrict__ rowptr_,
                                               int* __restrict__ cursor_) {
  int s = blockIdx.x;
  const int* counts = counts_ + (size_t)s * NN;
  int* rowptr = rowptr_ + (size_t)s * (NN + 1);
  int* cursor = cursor_ + (size_t)s * NN;
  __shared__ int sm[1024];
  const int C = 59;  // 1024*59 = 60416 >= NN
  int t = threadIdx.x;
  int base = t * C;
  int lsum = 0;
  for (int j = 0; j < C; ++j) {
    int idx = base + j;
    if (idx < NN) lsum += counts[idx];
  }
  sm[t] = lsum;
  __syncthreads();
  for (int off = 1; off < 1024; off <<= 1) {
    int v = (t >= off) ? sm[t - off] : 0;
    __syncthreads();
    sm[t] += v;
    __syncthreads();
  }
  int run = sm[t] - lsum;
  for (int j = 0; j < C; ++j) {
    int idx = base + j;
    if (idx < NN) {
      rowptr[idx] = run;
      cursor[idx] = run;
      run += counts[idx];
    }
  }
  if (t == 1023) rowptr[NN] = sm[1023];
}

__global__ __launch_bounds__(256) void k_scatter(const int* __restrict__ ei0,
                                                 const int* __restrict__ ei1,
                                                 int* __restrict__ cursor,
                                                 int* __restrict__ col) {
  int s = blockIdx.y;
  const int* ei = s ? ei1 : ei0;
  int i = blockIdx.x * 256 + threadIdx.x;
  if (i < NE) {
    int dst = ei[NE + i];
    int src = ei[i];
    int pos = atomicAdd(&cursor[s * NN + dst], 1);
    col[(size_t)s * NE + pos] = src;
  }
}

// ---------------------------------------------------------------- aggregation
template <int W>
__global__ __launch_bounds__(256) void k_agg(const float* __restrict__ h0,
                                             const float* __restrict__ h1,
                                             const int* __restrict__ rowptr_,
                                             const int* __restrict__ col_,
                                             float* __restrict__ agg_) {
  int s = blockIdx.y;
  const float* h = s ? h1 : h0;
  const int* rowptr = rowptr_ + (size_t)s * (NN + 1);
  const int* col = col_ + (size_t)s * NE;
  float* agg = agg_ + (size_t)s * NN * W;
  int wave = threadIdx.x >> 6;
  int lane = threadIdx.x & 63;
  int node = blockIdx.x * 4 + wave;
  if (node >= NN) return;
  int s0 = rowptr[node], s1 = rowptr[node + 1];
  if (W == 128) {
    float2 acc = make_float2(0.f, 0.f);
    const float* hp = h + (lane << 1);
    int j = s0;
    for (; j + 3 < s1; j += 4) {
      int a0 = col[j], a1 = col[j + 1], a2 = col[j + 2], a3 = col[j + 3];
      float2 v0 = *reinterpret_cast<const float2*>(hp + (size_t)a0 * 128);
      float2 v1 = *reinterpret_cast<const float2*>(hp + (size_t)a1 * 128);
      float2 v2 = *reinterpret_cast<const float2*>(hp + (size_t)a2 * 128);
      float2 v3 = *reinterpret_cast<const float2*>(hp + (size_t)a3 * 128);
      acc.x += (v0.x + v1.x) + (v2.x + v3.x);
      acc.y += (v0.y + v1.y) + (v2.y + v3.y);
    }
    for (; j < s1; ++j) {
      int a0 = col[j];
      float2 v0 = *reinterpret_cast<const float2*>(hp + (size_t)a0 * 128);
      acc.x += v0.x;
      acc.y += v0.y;
    }
    *reinterpret_cast<float2*>(agg + (size_t)node * 128 + (lane << 1)) = acc;
  } else {
    float2 acc = make_float2(0.f, 0.f);
    if (lane < 19) {
      const float* hp = h + (lane << 1);
      int j = s0;
      for (; j + 1 < s1; j += 2) {
        int a0 = col[j], a1 = col[j + 1];
        float2 v0 = *reinterpret_cast<const float2*>(hp + (size_t)a0 * W);
        float2 v1 = *reinterpret_cast<const float2*>(hp + (size_t)a1 * W);
        acc.x += v0.x + v1.x;
        acc.y += v0.y + v1.y;
      }
      if (j < s1) {
        float2 v = *reinterpret_cast<const float2*>(hp + (size_t)col[j] * W);
        acc.x += v.x;
        acc.y += v.y;
      }
      *reinterpret_cast<float2*>(agg + (size_t)node * W + (lane << 1)) = acc;
    }
  }
}

// ---------------------------------------------------------------- MFMA GEMM
// Z = A@Wr + X@Ws + b via split-bf16 (fp32 = hi + lo): 3 MFMAs per product
// (hh + hl + lh), fp32 accumulate. Also per-channel sum/sumsq into stats.
template <bool VEC>
__global__ __launch_bounds__(256) void k_gemm_mfma(
    const float* __restrict__ A_, int lda, const float* __restrict__ X0,
    const float* __restrict__ X1, int ldx, const float* __restrict__ Wr,
    const float* __restrict__ Ws, const float* __restrict__ bias, int K,
    float* __restrict__ Z_, float* __restrict__ stats_) {
  int side = blockIdx.y;
  const float* A = A_ + (size_t)side * NN * lda;
  const float* X = side ? X1 : X0;
  float* Z = Z_ + (size_t)side * NN * HH;
  float* stats = stats_ + (size_t)side * 256;

  __shared__ __align__(16) unsigned char sAh[64 * 64];
  __shared__ __align__(16) unsigned char sAl[64 * 64];
  __shared__ __align__(16) unsigned char sXh[64 * 64];
  __shared__ __align__(16) unsigned char sXl[64 * 64];
  __shared__ __align__(16) unsigned char sBh[2][128 * 64];  // [0]=Wr [1]=Ws
  __shared__ __align__(16) unsigned char sBl[2][128 * 64];

  int t = threadIdx.x;
  int l = t & 63;
  int wid = t >> 6;
  int wr = wid >> 1, wc = wid & 1;
  int row0 = blockIdx.x * 64;

  f32x4 acc[2][4];
#pragma unroll
  for (int rt = 0; rt < 2; ++rt)
#pragma unroll
    for (int ct = 0; ct < 4; ++ct) acc[rt][ct] = (f32x4)(0.f);

  int nK = (K + 31) >> 5;
  for (int ks = 0; ks < nK; ++ks) {
    // ---- stage A/X tile: 64 rows x 32 k, split hi/lo bf16
    {
      int r = t >> 2;
      int kc = (t & 3) << 3;  // k-span base (8 k per thread)
      int grow = row0 + r;
      float av[8], xv[8];
      if (VEC) {
        float4 a0 = make_float4(0, 0, 0, 0), a1 = a0, x0 = a0, x1 = a0;
        if (grow < NN) {
          const float* pa = A + (size_t)grow * lda + (ks << 5) + kc;
          const float* px = X + (size_t)grow * ldx + (ks << 5) + kc;
          a0 = *reinterpret_cast<const float4*>(pa);
          a1 = *reinterpret_cast<const float4*>(pa + 4);
          x0 = *reinterpret_cast<const float4*>(px);
          x1 = *reinterpret_cast<const float4*>(px + 4);
        }
        av[0] = a0.x; av[1] = a0.y; av[2] = a0.z; av[3] = a0.w;
        av[4] = a1.x; av[5] = a1.y; av[6] = a1.z; av[7] = a1.w;
        xv[0] = x0.x; xv[1] = x0.y; xv[2] = x0.z; xv[3] = x0.w;
        xv[4] = x1.x; xv[5] = x1.y; xv[6] = x1.z; xv[7] = x1.w;
      } else {
#pragma unroll
        for (int e = 0; e < 8; ++e) {
          int gk = (ks << 5) + kc + e;
          bool ok = (grow < NN) && (gk < K);
          av[e] = ok ? A[(size_t)grow * lda + gk] : 0.f;
          xv[e] = ok ? X[(size_t)grow * ldx + gk] : 0.f;
        }
      }
      bf16x8 ah, al, xh, xl;
#pragma unroll
      for (int e = 0; e < 8; ++e) {
        unsigned short h = f2bf(av[e]);
        ah[e] = (short)h;
        al[e] = (short)f2bf(av[e] - bf2f(h));
        h = f2bf(xv[e]);
        xh[e] = (short)h;
        xl[e] = (short)f2bf(xv[e] - bf2f(h));
      }
      int off = ((r << 6) + (kc << 1)) ^ ((r & 7) << 4);
      *reinterpret_cast<bf16x8*>(sAh + off) = ah;
      *reinterpret_cast<bf16x8*>(sAl + off) = al;
      *reinterpret_cast<bf16x8*>(sXh + off) = xh;
      *reinterpret_cast<bf16x8*>(sXl + off) = xl;
    }
    // ---- stage weights: 32 k x 128 cols, transposed to [col][k], split
    {
      int kq = t >> 5;         // k-quad 0..7
      int c0 = (t & 31) << 2;  // col base
      float wf[2][4][4];       // [mat][krow][col]
#pragma unroll
      for (int kk = 0; kk < 4; ++kk) {
        int gk = (ks << 5) + (kq << 2) + kk;
        float4 vr = make_float4(0, 0, 0, 0), vs = vr;
        if (gk < K) {
          vr = *reinterpret_cast<const float4*>(Wr + (size_t)gk * HH + c0);
          vs = *reinterpret_cast<const float4*>(Ws + (size_t)gk * HH + c0);
        }
        wf[0][kk][0] = vr.x; wf[0][kk][1] = vr.y; wf[0][kk][2] = vr.z; wf[0][kk][3] = vr.w;
        wf[1][kk][0] = vs.x; wf[1][kk][1] = vs.y; wf[1][kk][2] = vs.z; wf[1][kk][3] = vs.w;
      }
#pragma unroll
      for (int m = 0; m < 2; ++m) {
#pragma unroll
        for (int j = 0; j < 4; ++j) {
          int c = c0 + j;
          unsigned h0 = f2bf(wf[m][0][j]), h1 = f2bf(wf[m][1][j]);
          unsigned h2 = f2bf(wf[m][2][j]), h3 = f2bf(wf[m][3][j]);
          unsigned l0 = f2bf(wf[m][0][j] - bf2f((unsigned short)h0));
          unsigned l1 = f2bf(wf[m][1][j] - bf2f((unsigned short)h1));
          unsigned l2 = f2bf(wf[m][2][j] - bf2f((unsigned short)h2));
          unsigned l3 = f2bf(wf[m][3][j] - bf2f((unsigned short)h3));
          uint2 hv = make_uint2(h0 | (h1 << 16), h2 | (h3 << 16));
          uint2 lv = make_uint2(l0 | (l1 << 16), l2 | (l3 << 16));
          int off = ((c << 6) + (kq << 3)) ^ ((c & 7) << 4);
          *reinterpret_cast<uint2*>(sBh[m] + off) = hv;
          *reinterpret_cast<uint2*>(sBl[m] + off) = lv;
        }
      }
    }
    __syncthreads();
    // ---- MFMA phase
    bf16x8 fah[2], fal[2], fxh[2], fxl[2];
    int ko = (l >> 4) << 4;  // byte offset of this lane's 8-k span
#pragma unroll
    for (int rt = 0; rt < 2; ++rt) {
      int rr = (wr << 5) + (rt << 4) + (l & 15);
      int off = ((rr << 6) + ko) ^ ((rr & 7) << 4);
      fah[rt] = *reinterpret_cast<const bf16x8*>(sAh + off);
      fal[rt] = *reinterpret_cast<const bf16x8*>(sAl + off);
      fxh[rt] = *reinterpret_cast<const bf16x8*>(sXh + off);
      fxl[rt] = *reinterpret_cast<const bf16x8*>(sXl + off);
    }
#pragma unroll
    for (int ct = 0; ct < 4; ++ct) {
      int cc = (wc << 6) + (ct << 4) + (l & 15);
      int off = ((cc << 6) + ko) ^ ((cc & 7) << 4);
      bf16x8 brh = *reinterpret_cast<const bf16x8*>(sBh[0] + off);
      bf16x8 brl = *reinterpret_cast<const bf16x8*>(sBl[0] + off);
      bf16x8 bsh = *reinterpret_cast<const bf16x8*>(sBh[1] + off);
      bf16x8 bsl = *reinterpret_cast<const bf16x8*>(sBl[1] + off);
#pragma unroll
      for (int rt = 0; rt < 2; ++rt) {
        f32x4 c = acc[rt][ct];
        c = __builtin_amdgcn_mfma_f32_16x16x32_bf16(fah[rt], brh, c, 0, 0, 0);
        c = __builtin_amdgcn_mfma_f32_16x16x32_bf16(fah[rt], brl, c, 0, 0, 0);
        c = __builtin_amdgcn_mfma_f32_16x16x32_bf16(fal[rt], brh, c, 0, 0, 0);
        c = __builtin_amdgcn_mfma_f32_16x16x32_bf16(fxh[rt], bsh, c, 0, 0, 0);
        c = __builtin_amdgcn_mfma_f32_16x16x32_bf16(fxh[rt], bsl, c, 0, 0, 0);
        c = __builtin_amdgcn_mfma_f32_16x16x32_bf16(fxl[rt], bsh, c, 0, 0, 0);
        acc[rt][ct] = c;
      }
    }
    __syncthreads();
  }

  // ---- epilogue: bias, store Z, per-channel stats
  float ps[4] = {0, 0, 0, 0}, pq[4] = {0, 0, 0, 0};
#pragma unroll
  for (int ct = 0; ct < 4; ++ct) {
    int col = (wc << 6) + (ct << 4) + (l & 15);
    float b = bias[col];
#pragma unroll
    for (int rt = 0; rt < 2; ++rt) {
      int rbase = row0 + (wr << 5) + (rt << 4) + ((l >> 4) << 2);
      f32x4 v = acc[rt][ct];
#pragma unroll
      for (int rg = 0; rg < 4; ++rg) {
        int row = rbase + rg;
        if (row < NN) {
          float z = v[rg] + b;
          Z[(size_t)row * HH + col] = z;
          ps[ct] += z;
          pq[ct] += z * z;
        }
      }
    }
  }
#pragma unroll
  for (int ct = 0; ct < 4; ++ct) {
    ps[ct] += __shfl_xor(ps[ct], 16, 64);
    ps[ct] += __shfl_xor(ps[ct], 32, 64);
    pq[ct] += __shfl_xor(pq[ct], 16, 64);
    pq[ct] += __shfl_xor(pq[ct], 32, 64);
  }
  if (l < 16) {
#pragma unroll
    for (int ct = 0; ct < 4; ++ct) {
      int col = (wc << 6) + (ct << 4) + l;
      atomicAdd(&stats[col], ps[ct]);
      atomicAdd(&stats[HH + col], pq[ct]);
    }
  }
}

// ---------------------------------------------------------------- BN
__global__ void k_bnfin(const float* __restrict__ stats_, const float* __restrict__ g,
                        const float* __restrict__ be, float* __restrict__ ss_) {
  int s = blockIdx.x;
  const float* stats = stats_ + (size_t)s * 256;
  float* ss = ss_ + (size_t)s * 256;
  int c = threadIdx.x;
  if (c < HH) {
    float mu = stats[c] * (1.0f / NN);
    float var = stats[HH + c] * (1.0f / NN) - mu * mu;
    float inv = 1.0f / sqrtf(var + 1e-5f);
    float sc = g[c] * inv;
    ss[c] = sc;
    ss[HH + c] = be[c] - mu * sc;
  }
}

__global__ __launch_bounds__(256) void k_bnrelu(float* __restrict__ ZH_,
                                                const float* __restrict__ ss_) {
  int s = blockIdx.y;
  float* ZH = ZH_ + (size_t)s * NN * HH;
  const float* ss = ss_ + (size_t)s * 256;
  size_t i = (size_t)blockIdx.x * 256 + threadIdx.x;
  float4 z = *reinterpret_cast<float4*>(ZH + i * 4);
  int c = (int)((i * 4) & 127);
  float4 sc = *reinterpret_cast<const float4*>(ss + c);
  float4 sh = *reinterpret_cast<const float4*>(ss + HH + c);
  z.x = fmaxf(z.x * sc.x + sh.x, 0.f);
  z.y = fmaxf(z.y * sc.y + sh.y, 0.f);
  z.z = fmaxf(z.z * sc.z + sh.z, 0.f);
  z.w = fmaxf(z.w * sc.w + sh.w, 0.f);
  *reinterpret_cast<float4*>(ZH + i * 4) = z;
}

// ---------------------------------------------------------------- gate MLP
__global__ __launch_bounds__(256) void k_gate(const float* __restrict__ Ho_,
                                              const float* __restrict__ Wg1,
                                              const float* __restrict__ bg1,
                                              const float* __restrict__ Wg2,
                                              const float* __restrict__ bg2,
                                              float* __restrict__ gate_) {
  int s = blockIdx.y;
  const float* Ho = Ho_ + (size_t)s * NN * HH;
  float* gate = gate_ + (size_t)s * NN;
  __shared__ float sW[128 * 32];
  int t = threadIdx.x;
  for (int i = t; i < 128 * 32 / 4; i += 256)
    *reinterpret_cast<float4*>(&sW[i * 4]) =
        *reinterpret_cast<const float4*>(Wg1 + i * 4);
  __syncthreads();
  int lane = t & 63, wv = t >> 6;
  int half = lane >> 5, l = lane & 31;
  float w2 = Wg2[l];
  float b2 = bg2[0];
  float b1v = bg1[l];
  for (int it = 0; it < 16; ++it) {
    int node = blockIdx.x * 128 + it * 8 + wv * 2 + half;
    if (node < NN) {
      const float* hr = Ho + (size_t)node * 128;
      float acc = b1v;
      for (int k = 0; k < 128; k += 4) {
        float4 hv = *reinterpret_cast<const float4*>(hr + k);
        acc += hv.x * sW[(k) * 32 + l];
        acc += hv.y * sW[(k + 1) * 32 + l];
        acc += hv.z * sW[(k + 2) * 32 + l];
        acc += hv.w * sW[(k + 3) * 32 + l];
      }
      float v = fmaxf(acc, 0.f) * w2;
#pragma unroll
      for (int off = 16; off > 0; off >>= 1) v += __shfl_down(v, off, 32);
      if (l == 0) gate[node] = fmaxf(v + b2, 0.f);
    }
  }
}

// ---------------------------------------------------------------- pooling
__global__ void k_bounds(const int* __restrict__ batch0,
                         const int* __restrict__ batch1,
                         int* __restrict__ starts, int* __restrict__ ends) {
  int s = blockIdx.x;
  const int* batch = s ? batch1 : batch0;
  int g = threadIdx.x;
  if (g >= NB) return;
  int lo = 0, hi = NN;
  while (lo < hi) { int mid = (lo + hi) >> 1; if (batch[mid] < g) lo = mid + 1; else hi = mid; }
  starts[s * NB + g] = lo;
  lo = 0; hi = NN;
  while (lo < hi) { int mid = (lo + hi) >> 1; if (batch[mid] < g + 1) lo = mid + 1; else hi = mid; }
  ends[s * NB + g] = lo;
}

// per-graph gate max + exp-sum (64 small blocks; gate is 240KB -> L2-fast)
__global__ __launch_bounds__(256) void k_gstat(const float* __restrict__ gate_,
                                               const int* __restrict__ starts,
                                               const int* __restrict__ ends,
                                               float* __restrict__ gm,
                                               float* __restrict__ dn) {
  int sd = blockIdx.y;
  int b = blockIdx.x;
  const float* gate = gate_ + (size_t)sd * NN;
  __shared__ float red[256];
  int t = threadIdx.x;
  int s = starts[sd * NB + b], en = ends[sd * NB + b];
  float m = -3.402823e38f;
  for (int i = s + t; i < en; i += 256) m = fmaxf(m, gate[i]);
  red[t] = m;
  __syncthreads();
  for (int off = 128; off > 0; off >>= 1) {
    if (t < off) red[t] = fmaxf(red[t], red[t + off]);
    __syncthreads();
  }
  float gmax = red[0];
  __syncthreads();
  float ds = 0;
  for (int i = s + t; i < en; i += 256) ds += expf(gate[i] - gmax);
  red[t] = ds;
  __syncthreads();
  for (int off = 128; off > 0; off >>= 1) {
    if (t < off) red[t] += red[t + off];
    __syncthreads();
  }
  if (t == 0) {
    gm[sd * NB + b] = gmax;
    dn[sd * NB + b] = red[0];
  }
}

// weighted sum, graph split into SPL node-slices -> 512 blocks, atomicAdd to e
#define SPL 8
__global__ __launch_bounds__(256) void k_poolsum(const float* __restrict__ Ho_,
                                                 const float* __restrict__ gate_,
                                                 const int* __restrict__ starts,
                                                 const int* __restrict__ ends,
                                                 const float* __restrict__ gm,
                                                 const float* __restrict__ dn,
                                                 float* __restrict__ e) {
  int sd = blockIdx.y;
  int b = blockIdx.x;
  int z = blockIdx.z;
  const float* Ho = Ho_ + (size_t)sd * NN * HH;
  const float* gate = gate_ + (size_t)sd * NN;
  __shared__ float red[256];
  int t = threadIdx.x;
  int s = starts[sd * NB + b], en = ends[sd * NB + b];
  int len = en - s;
  if (len <= 0) return;  // e pre-zeroed by memset
  int chunk = (len + SPL - 1) / SPL;
  int i0 = s + z * chunk;
  int i1 = min(en, i0 + chunk);
  if (i0 >= i1) return;
  float gmax = gm[sd * NB + b];
  float invdn = 1.0f / dn[sd * NB + b];
  int c = t & 127, half = t >> 7;
  float acc = 0;
  for (int i = i0 + half; i < i1; i += 2)
    acc += expf(gate[i] - gmax) * Ho[(size_t)i * 128 + c];
  red[t] = acc;
  __syncthreads();
  if (t < 128)
    atomicAdd(&e[(size_t)sd * NB * HH + (size_t)b * HH + t],
              (red[t] + red[t + 128]) * invdn);
}

// ---------------------------------------------------------------- final MLP
__global__ void k_final(const float* __restrict__ e, const float* __restrict__ Wf1,
                        const float* __restrict__ bf1, const float* __restrict__ Wf2,
                        const float* __restrict__ bf2, float* __restrict__ out) {
  int b = blockIdx.x, j = threadIdx.x;  // 64 threads
  float acc = bf1[j];
  const float* e1 = e + (size_t)b * 128;
  const float* e2 = e + (size_t)NB * 128 + (size_t)b * 128;
  for (int k = 0; k < 128; ++k) {
    float d = fabsf(e1[k] - e2[k]);
    acc += d * Wf1[k * 64 + j];
  }
  float v = fmaxf(acc, 0.f) * Wf2[j];
#pragma unroll
  for (int off = 32; off > 0; off >>= 1) v += __shfl_down(v, off, 64);
  if (j == 0) out[b] = v + bf2[0];
}

// ---------------------------------------------------------------- launch
extern "C" void kernel_launch(void* const* d_in, const int* in_sizes, int n_in,
                              void* d_out, int out_size, void* d_ws, size_t ws_size,
                              hipStream_t stream) {
  const float* x0 = (const float*)d_in[0];
  const float* x1 = (const float*)d_in[1];
  const int* ei0 = (const int*)d_in[2];
  const int* ei1 = (const int*)d_in[3];
  const int* batch0 = (const int*)d_in[4];
  const int* batch1 = (const int*)d_in[5];
  const float* W1r = (const float*)d_in[6];
  const float* W1s = (const float*)d_in[7];
  const float* b1 = (const float*)d_in[8];
  const float* g1 = (const float*)d_in[9];
  const float* be1 = (const float*)d_in[10];
  const float* W2r = (const float*)d_in[11];
  const float* W2s = (const float*)d_in[12];
  const float* b2 = (const float*)d_in[13];
  const float* g2 = (const float*)d_in[14];
  const float* be2 = (const float*)d_in[15];
  const float* W3r = (const float*)d_in[16];
  const float* W3s = (const float*)d_in[17];
  const float* b3 = (const float*)d_in[18];
  const float* g3 = (const float*)d_in[19];
  const float* be3 = (const float*)d_in[20];
  const float* Wg1 = (const float*)d_in[21];
  const float* bg1 = (const float*)d_in[22];
  const float* Wg2 = (const float*)d_in[23];
  const float* bg2 = (const float*)d_in[24];
  const float* Wf1 = (const float*)d_in[25];
  const float* bf1 = (const float*)d_in[26];
  const float* Wf2 = (const float*)d_in[27];
  const float* bf2 = (const float*)d_in[28];

  char* p = (char*)d_ws;
  auto alloc = [&](size_t bytes) {
    void* r = (void*)p;
    p += (bytes + 255) & ~(size_t)255;
    return r;
  };
  int* counts = (int*)alloc((size_t)2 * NN * 4);
  int* rowptr = (int*)alloc((size_t)2 * (NN + 1) * 4);
  int* cursor = (int*)alloc((size_t)2 * NN * 4);
  int* col = (int*)alloc((size_t)2 * NE * 4);
  int* starts = (int*)alloc(2 * NB * 4);
  int* ends = (int*)alloc(2 * NB * 4);
  float* stats = (float*)alloc(2 * 256 * 4);
  float* ss = (float*)alloc(2 * 256 * 4);
  float* gate = (float*)alloc((size_t)2 * NN * 4);
  float* gm = (float*)alloc(2 * NB * 4);
  float* dn = (float*)alloc(2 * NB * 4);
  float* ebuf = (float*)alloc((size_t)2 * NB * HH * 4);
  float* bufA = (float*)alloc((size_t)2 * NN * HH * 4);
  float* bufB = (float*)alloc((size_t)2 * NN * HH * 4);
  float* bufC = (float*)alloc((size_t)2 * NN * HH * 4);

  // ---- CSR build (both sides)
  hipMemsetAsync(counts, 0, (size_t)2 * NN * 4, stream);
  k_hist<<<dim3((NE + 255) / 256, 2), 256, 0, stream>>>(ei0, ei1, counts);
  k_scan<<<2, 1024, 0, stream>>>(counts, rowptr, cursor);
  k_scatter<<<dim3((NE + 255) / 256, 2), 256, 0, stream>>>(ei0, ei1, cursor, col);

  // ---- layer 1: F=38 -> 128
  k_agg<38><<<dim3(15000, 2), 256, 0, stream>>>(x0, x1, rowptr, col, bufA);
  hipMemsetAsync(stats, 0, 2 * 256 * 4, stream);
  k_gemm_mfma<false><<<dim3(938, 2), 256, 0, stream>>>(
      bufA, FIN, x0, x1, FIN, W1r, W1s, b1, FIN, bufB, stats);
  k_bnfin<<<2, 128, 0, stream>>>(stats, g1, be1, ss);
  k_bnrelu<<<dim3(7500, 2), 256, 0, stream>>>(bufB, ss);

  // ---- layer 2: 128 -> 128
  k_agg<128><<<dim3(15000, 2), 256, 0, stream>>>(bufB, bufB + (size_t)NN * HH,
                                                 rowptr, col, bufA);
  hipMemsetAsync(stats, 0, 2 * 256 * 4, stream);
  k_gemm_mfma<true><<<dim3(938, 2), 256, 0, stream>>>(
      bufA, HH, bufB, bufB + (size_t)NN * HH, HH, W2r, W2s, b2, HH, bufC, stats);
  k_bnfin<<<2, 128, 0, stream>>>(stats, g2, be2, ss);
  k_bnrelu<<<dim3(7500, 2), 256, 0, stream>>>(bufC, ss);

  // ---- layer 3: 128 -> 128
  k_agg<128><<<dim3(15000, 2), 256, 0, stream>>>(bufC, bufC + (size_t)NN * HH,
                                                 rowptr, col, bufA);
  hipMemsetAsync(stats, 0, 2 * 256 * 4, stream);
  k_gemm_mfma<true><<<dim3(938, 2), 256, 0, stream>>>(
      bufA, HH, bufC, bufC + (size_t)NN * HH, HH, W3r, W3s, b3, HH, bufB, stats);
  k_bnfin<<<2, 128, 0, stream>>>(stats, g3, be3, ss);
  k_bnrelu<<<dim3(7500, 2), 256, 0, stream>>>(bufB, ss);

  // ---- gate + attention pool (both sides), parallel pooling
  k_gate<<<dim3(469, 2), 256, 0, stream>>>(bufB, Wg1, bg1, Wg2, bg2, gate);
  k_bounds<<<2, 32, 0, stream>>>(batch0, batch1, starts, ends);
  hipMemsetAsync(ebuf, 0, (size_t)2 * NB * HH * 4, stream);
  k_gstat<<<dim3(NB, 2), 256, 0, stream>>>(gate, starts, ends, gm, dn);
  k_poolsum<<<dim3(NB, 2, SPL), 256, 0, stream>>>(bufB, gate, starts, ends, gm, dn,
                                                  ebuf);

  k_final<<<NB, 64, 0, stream>>>(ebuf, Wf1, bf1, Wf2, bf2, (float*)d_out);
}

// Round 11
// 1260.601 us; speedup vs baseline: 1.5296x; 1.1022x over previous
//
#include <hip/hip_runtime.h>
#include <cstdint>
#include <cstddef>

#define NN 60000
#define NE 960000
#define NB 32
#define FIN 38
#define HH 128
#define SCB 235  // scan blocks/side: 235*256 = 60160 >= NN

typedef short bf16x8 __attribute__((ext_vector_type(8)));
typedef float f32x4 __attribute__((ext_vector_type(4)));

__device__ __forceinline__ unsigned short f2bf(float x) {
  unsigned u = __builtin_bit_cast(unsigned, x);
  u = u + 0x7fffu + ((u >> 16) & 1u);
  return (unsigned short)(u >> 16);
}
__device__ __forceinline__ float bf2f(unsigned short h) {
  unsigned u = ((unsigned)h) << 16;
  return __builtin_bit_cast(float, u);
}

// ---------------------------------------------------------------- CSR build
__global__ __launch_bounds__(256) void k_hist(const int* __restrict__ ei0,
                                              const int* __restrict__ ei1,
                                              int* __restrict__ counts) {
  int s = blockIdx.y;
  const int* ei = s ? ei1 : ei0;
  int i = blockIdx.x * 256 + threadIdx.x;
  if (i < NE) atomicAdd(&counts[s * NN + ei[NE + i]], 1);
}

// 3-stage parallel scan: per-block exclusive scan -> scan of block sums -> add
__global__ __launch_bounds__(256) void k_scan1(const int* __restrict__ counts_,
                                               int* __restrict__ rowptr_,
                                               int* __restrict__ bsum) {
  int s = blockIdx.y, b = blockIdx.x, t = threadIdx.x;
  int idx = b * 256 + t;
  const int* counts = counts_ + (size_t)s * NN;
  int* rowptr = rowptr_ + (size_t)s * (NN + 1);
  __shared__ int sm[256];
  int c = (idx < NN) ? counts[idx] : 0;
  sm[t] = c;
  __syncthreads();
  for (int off = 1; off < 256; off <<= 1) {
    int v = (t >= off) ? sm[t - off] : 0;
    __syncthreads();
    sm[t] += v;
    __syncthreads();
  }
  if (idx < NN) rowptr[idx] = sm[t] - c;  // exclusive within block
  if (t == 255) bsum[s * SCB + b] = sm[255];
}

__global__ __launch_bounds__(256) void k_scan2(const int* __restrict__ bsum,
                                               int* __restrict__ boff,
                                               int* __restrict__ rowptr_) {
  int s = blockIdx.x, t = threadIdx.x;
  __shared__ int sm[256];
  int v = (t < SCB) ? bsum[s * SCB + t] : 0;
  sm[t] = v;
  __syncthreads();
  for (int off = 1; off < 256; off <<= 1) {
    int u = (t >= off) ? sm[t - off] : 0;
    __syncthreads();
    sm[t] += u;
    __syncthreads();
  }
  if (t < SCB) boff[s * SCB + t] = sm[t] - v;
  if (t == 255) rowptr_[(size_t)s * (NN + 1) + NN] = sm[255];
}

__global__ __launch_bounds__(256) void k_scan3(int* __restrict__ rowptr_,
                                               int* __restrict__ cursor_,
                                               const int* __restrict__ boff) {
  int s = blockIdx.y, b = blockIdx.x, t = threadIdx.x;
  int idx = b * 256 + t;
  if (idx < NN) {
    int v = rowptr_[(size_t)s * (NN + 1) + idx] + boff[s * SCB + b];
    rowptr_[(size_t)s * (NN + 1) + idx] = v;
    cursor_[(size_t)s * NN + idx] = v;
  }
}

// col stored as u16 (src < 60000 < 2^16): halves scatter write amplification
__global__ __launch_bounds__(256) void k_scatter(const int* __restrict__ ei0,
                                                 const int* __restrict__ ei1,
                                                 int* __restrict__ cursor,
                                                 unsigned short* __restrict__ col) {
  int s = blockIdx.y;
  const int* ei = s ? ei1 : ei0;
  int i = blockIdx.x * 256 + threadIdx.x;
  if (i < NE) {
    int dst = ei[NE + i];
    int src = ei[i];
    int pos = atomicAdd(&cursor[s * NN + dst], 1);
    col[(size_t)s * NE + pos] = (unsigned short)src;
  }
}

// ---------------------------------------------------------------- aggregation
template <int W>
__global__ __launch_bounds__(256) void k_agg(const float* __restrict__ h0,
                                             const float* __restrict__ h1,
                                             const int* __restrict__ rowptr_,
                                             const unsigned short* __restrict__ col_,
                                             float* __restrict__ agg_) {
  int s = blockIdx.y;
  const float* h = s ? h1 : h0;
  const int* rowptr = rowptr_ + (size_t)s * (NN + 1);
  const unsigned short* col = col_ + (size_t)s * NE;
  float* agg = agg_ + (size_t)s * NN * W;
  int wave = threadIdx.x >> 6;
  int lane = threadIdx.x & 63;
  int node = blockIdx.x * 4 + wave;
  if (node >= NN) return;
  int s0 = rowptr[node], s1 = rowptr[node + 1];
  if (W == 128) {
    float2 acc = make_float2(0.f, 0.f);
    const float* hp = h + (lane << 1);
    int j = s0;
    for (; j + 3 < s1; j += 4) {
      int a0 = col[j], a1 = col[j + 1], a2 = col[j + 2], a3 = col[j + 3];
      float2 v0 = *reinterpret_cast<const float2*>(hp + (size_t)a0 * 128);
      float2 v1 = *reinterpret_cast<const float2*>(hp + (size_t)a1 * 128);
      float2 v2 = *reinterpret_cast<const float2*>(hp + (size_t)a2 * 128);
      float2 v3 = *reinterpret_cast<const float2*>(hp + (size_t)a3 * 128);
      acc.x += (v0.x + v1.x) + (v2.x + v3.x);
      acc.y += (v0.y + v1.y) + (v2.y + v3.y);
    }
    for (; j < s1; ++j) {
      int a0 = col[j];
      float2 v0 = *reinterpret_cast<const float2*>(hp + (size_t)a0 * 128);
      acc.x += v0.x;
      acc.y += v0.y;
    }
    *reinterpret_cast<float2*>(agg + (size_t)node * 128 + (lane << 1)) = acc;
  } else {
    float2 acc = make_float2(0.f, 0.f);
    if (lane < 19) {
      const float* hp = h + (lane << 1);
      int j = s0;
      for (; j + 1 < s1; j += 2) {
        int a0 = col[j], a1 = col[j + 1];
        float2 v0 = *reinterpret_cast<const float2*>(hp + (size_t)a0 * W);
        float2 v1 = *reinterpret_cast<const float2*>(hp + (size_t)a1 * W);
        acc.x += v0.x + v1.x;
        acc.y += v0.y + v1.y;
      }
      if (j < s1) {
        float2 v = *reinterpret_cast<const float2*>(hp + (size_t)col[j] * W);
        acc.x += v.x;
        acc.y += v.y;
      }
      *reinterpret_cast<float2*>(agg + (size_t)node * W + (lane << 1)) = acc;
    }
  }
}

// ---------------------------------------------------------------- MFMA GEMM
// Z = A@Wr + X@Ws + b via split-bf16 (fp32 = hi + lo): 3 MFMAs per product
// (hh + hl + lh), fp32 accumulate. Also per-channel sum/sumsq into stats.
template <bool VEC>
__global__ __launch_bounds__(256) void k_gemm_mfma(
    const float* __restrict__ A_, int lda, const float* __restrict__ X0,
    const float* __restrict__ X1, int ldx, const float* __restrict__ Wr,
    const float* __restrict__ Ws, const float* __restrict__ bias, int K,
    float* __restrict__ Z_, float* __restrict__ stats_) {
  int side = blockIdx.y;
  const float* A = A_ + (size_t)side * NN * lda;
  const float* X = side ? X1 : X0;
  float* Z = Z_ + (size_t)side * NN * HH;
  float* stats = stats_ + (size_t)side * 256;

  __shared__ __align__(16) unsigned char sAh[64 * 64];
  __shared__ __align__(16) unsigned char sAl[64 * 64];
  __shared__ __align__(16) unsigned char sXh[64 * 64];
  __shared__ __align__(16) unsigned char sXl[64 * 64];
  __shared__ __align__(16) unsigned char sBh[2][128 * 64];  // [0]=Wr [1]=Ws
  __shared__ __align__(16) unsigned char sBl[2][128 * 64];

  int t = threadIdx.x;
  int l = t & 63;
  int wid = t >> 6;
  int wr = wid >> 1, wc = wid & 1;
  int row0 = blockIdx.x * 64;

  f32x4 acc[2][4];
#pragma unroll
  for (int rt = 0; rt < 2; ++rt)
#pragma unroll
    for (int ct = 0; ct < 4; ++ct) acc[rt][ct] = (f32x4)(0.f);

  int nK = (K + 31) >> 5;
  for (int ks = 0; ks < nK; ++ks) {
    {
      int r = t >> 2;
      int kc = (t & 3) << 3;
      int grow = row0 + r;
      float av[8], xv[8];
      if (VEC) {
        float4 a0 = make_float4(0, 0, 0, 0), a1 = a0, x0 = a0, x1 = a0;
        if (grow < NN) {
          const float* pa = A + (size_t)grow * lda + (ks << 5) + kc;
          const float* px = X + (size_t)grow * ldx + (ks << 5) + kc;
          a0 = *reinterpret_cast<const float4*>(pa);
          a1 = *reinterpret_cast<const float4*>(pa + 4);
          x0 = *reinterpret_cast<const float4*>(px);
          x1 = *reinterpret_cast<const float4*>(px + 4);
        }
        av[0] = a0.x; av[1] = a0.y; av[2] = a0.z; av[3] = a0.w;
        av[4] = a1.x; av[5] = a1.y; av[6] = a1.z; av[7] = a1.w;
        xv[0] = x0.x; xv[1] = x0.y; xv[2] = x0.z; xv[3] = x0.w;
        xv[4] = x1.x; xv[5] = x1.y; xv[6] = x1.z; xv[7] = x1.w;
      } else {
#pragma unroll
        for (int e = 0; e < 8; ++e) {
          int gk = (ks << 5) + kc + e;
          bool ok = (grow < NN) && (gk < K);
          av[e] = ok ? A[(size_t)grow * lda + gk] : 0.f;
          xv[e] = ok ? X[(size_t)grow * ldx + gk] : 0.f;
        }
      }
      bf16x8 ah, al, xh, xl;
#pragma unroll
      for (int e = 0; e < 8; ++e) {
        unsigned short h = f2bf(av[e]);
        ah[e] = (short)h;
        al[e] = (short)f2bf(av[e] - bf2f(h));
        h = f2bf(xv[e]);
        xh[e] = (short)h;
        xl[e] = (short)f2bf(xv[e] - bf2f(h));
      }
      int off = ((r << 6) + (kc << 1)) ^ ((r & 7) << 4);
      *reinterpret_cast<bf16x8*>(sAh + off) = ah;
      *reinterpret_cast<bf16x8*>(sAl + off) = al;
      *reinterpret_cast<bf16x8*>(sXh + off) = xh;
      *reinterpret_cast<bf16x8*>(sXl + off) = xl;
    }
    {
      int kq = t >> 5;
      int c0 = (t & 31) << 2;
      float wf[2][4][4];
#pragma unroll
      for (int kk = 0; kk < 4; ++kk) {
        int gk = (ks << 5) + (kq << 2) + kk;
        float4 vr = make_float4(0, 0, 0, 0), vs = vr;
        if (gk < K) {
          vr = *reinterpret_cast<const float4*>(Wr + (size_t)gk * HH + c0);
          vs = *reinterpret_cast<const float4*>(Ws + (size_t)gk * HH + c0);
        }
        wf[0][kk][0] = vr.x; wf[0][kk][1] = vr.y; wf[0][kk][2] = vr.z; wf[0][kk][3] = vr.w;
        wf[1][kk][0] = vs.x; wf[1][kk][1] = vs.y; wf[1][kk][2] = vs.z; wf[1][kk][3] = vs.w;
      }
#pragma unroll
      for (int m = 0; m < 2; ++m) {
#pragma unroll
        for (int j = 0; j < 4; ++j) {
          int c = c0 + j;
          unsigned h0 = f2bf(wf[m][0][j]), h1 = f2bf(wf[m][1][j]);
          unsigned h2 = f2bf(wf[m][2][j]), h3 = f2bf(wf[m][3][j]);
          unsigned l0 = f2bf(wf[m][0][j] - bf2f((unsigned short)h0));
          unsigned l1 = f2bf(wf[m][1][j] - bf2f((unsigned short)h1));
          unsigned l2 = f2bf(wf[m][2][j] - bf2f((unsigned short)h2));
          unsigned l3 = f2bf(wf[m][3][j] - bf2f((unsigned short)h3));
          uint2 hv = make_uint2(h0 | (h1 << 16), h2 | (h3 << 16));
          uint2 lv = make_uint2(l0 | (l1 << 16), l2 | (l3 << 16));
          int off = ((c << 6) + (kq << 3)) ^ ((c & 7) << 4);
          *reinterpret_cast<uint2*>(sBh[m] + off) = hv;
          *reinterpret_cast<uint2*>(sBl[m] + off) = lv;
        }
      }
    }
    __syncthreads();
    bf16x8 fah[2], fal[2], fxh[2], fxl[2];
    int ko = (l >> 4) << 4;
#pragma unroll
    for (int rt = 0; rt < 2; ++rt) {
      int rr = (wr << 5) + (rt << 4) + (l & 15);
      int off = ((rr << 6) + ko) ^ ((rr & 7) << 4);
      fah[rt] = *reinterpret_cast<const bf16x8*>(sAh + off);
      fal[rt] = *reinterpret_cast<const bf16x8*>(sAl + off);
      fxh[rt] = *reinterpret_cast<const bf16x8*>(sXh + off);
      fxl[rt] = *reinterpret_cast<const bf16x8*>(sXl + off);
    }
#pragma unroll
    for (int ct = 0; ct < 4; ++ct) {
      int cc = (wc << 6) + (ct << 4) + (l & 15);
      int off = ((cc << 6) + ko) ^ ((cc & 7) << 4);
      bf16x8 brh = *reinterpret_cast<const bf16x8*>(sBh[0] + off);
      bf16x8 brl = *reinterpret_cast<const bf16x8*>(sBl[0] + off);
      bf16x8 bsh = *reinterpret_cast<const bf16x8*>(sBh[1] + off);
      bf16x8 bsl = *reinterpret_cast<const bf16x8*>(sBl[1] + off);
#pragma unroll
      for (int rt = 0; rt < 2; ++rt) {
        f32x4 c = acc[rt][ct];
        c = __builtin_amdgcn_mfma_f32_16x16x32_bf16(fah[rt], brh, c, 0, 0, 0);
        c = __builtin_amdgcn_mfma_f32_16x16x32_bf16(fah[rt], brl, c, 0, 0, 0);
        c = __builtin_amdgcn_mfma_f32_16x16x32_bf16(fal[rt], brh, c, 0, 0, 0);
        c = __builtin_amdgcn_mfma_f32_16x16x32_bf16(fxh[rt], bsh, c, 0, 0, 0);
        c = __builtin_amdgcn_mfma_f32_16x16x32_bf16(fxh[rt], bsl, c, 0, 0, 0);
        c = __builtin_amdgcn_mfma_f32_16x16x32_bf16(fxl[rt], bsh, c, 0, 0, 0);
        acc[rt][ct] = c;
      }
    }
    __syncthreads();
  }

  float ps[4] = {0, 0, 0, 0}, pq[4] = {0, 0, 0, 0};
#pragma unroll
  for (int ct = 0; ct < 4; ++ct) {
    int col = (wc << 6) + (ct << 4) + (l & 15);
    float b = bias[col];
#pragma unroll
    for (int rt = 0; rt < 2; ++rt) {
      int rbase = row0 + (wr << 5) + (rt << 4) + ((l >> 4) << 2);
      f32x4 v = acc[rt][ct];
#pragma unroll
      for (int rg = 0; rg < 4; ++rg) {
        int row = rbase + rg;
        if (row < NN) {
          float z = v[rg] + b;
          Z[(size_t)row * HH + col] = z;
          ps[ct] += z;
          pq[ct] += z * z;
        }
      }
    }
  }
#pragma unroll
  for (int ct = 0; ct < 4; ++ct) {
    ps[ct] += __shfl_xor(ps[ct], 16, 64);
    ps[ct] += __shfl_xor(ps[ct], 32, 64);
    pq[ct] += __shfl_xor(pq[ct], 16, 64);
    pq[ct] += __shfl_xor(pq[ct], 32, 64);
  }
  if (l < 16) {
#pragma unroll
    for (int ct = 0; ct < 4; ++ct) {
      int col = (wc << 6) + (ct << 4) + l;
      atomicAdd(&stats[col], ps[ct]);
      atomicAdd(&stats[HH + col], pq[ct]);
    }
  }
}

// ---------------------------------------------------------------- BN
__global__ void k_bnfin(const float* __restrict__ stats_, const float* __restrict__ g,
                        const float* __restrict__ be, float* __restrict__ ss_) {
  int s = blockIdx.x;
  const float* stats = stats_ + (size_t)s * 256;
  float* ss = ss_ + (size_t)s * 256;
  int c = threadIdx.x;
  if (c < HH) {
    float mu = stats[c] * (1.0f / NN);
    float var = stats[HH + c] * (1.0f / NN) - mu * mu;
    float inv = 1.0f / sqrtf(var + 1e-5f);
    float sc = g[c] * inv;
    ss[c] = sc;
    ss[HH + c] = be[c] - mu * sc;
  }
}

__global__ __launch_bounds__(256) void k_bnrelu(float* __restrict__ ZH_,
                                                const float* __restrict__ ss_) {
  int s = blockIdx.y;
  float* ZH = ZH_ + (size_t)s * NN * HH;
  const float* ss = ss_ + (size_t)s * 256;
  size_t i = (size_t)blockIdx.x * 256 + threadIdx.x;
  float4 z = *reinterpret_cast<float4*>(ZH + i * 4);
  int c = (int)((i * 4) & 127);
  float4 sc = *reinterpret_cast<const float4*>(ss + c);
  float4 sh = *reinterpret_cast<const float4*>(ss + HH + c);
  z.x = fmaxf(z.x * sc.x + sh.x, 0.f);
  z.y = fmaxf(z.y * sc.y + sh.y, 0.f);
  z.z = fmaxf(z.z * sc.z + sh.z, 0.f);
  z.w = fmaxf(z.w * sc.w + sh.w, 0.f);
  *reinterpret_cast<float4*>(ZH + i * 4) = z;
}

// ---------------------------------------------------------------- gate MLP
__global__ __launch_bounds__(256) void k_gate(const float* __restrict__ Ho_,
                                              const float* __restrict__ Wg1,
                                              const float* __restrict__ bg1,
                                              const float* __restrict__ Wg2,
                                              const float* __restrict__ bg2,
                                              float* __restrict__ gate_) {
  int s = blockIdx.y;
  const float* Ho = Ho_ + (size_t)s * NN * HH;
  float* gate = gate_ + (size_t)s * NN;
  __shared__ float sW[128 * 32];
  int t = threadIdx.x;
  for (int i = t; i < 128 * 32 / 4; i += 256)
    *reinterpret_cast<float4*>(&sW[i * 4]) =
        *reinterpret_cast<const float4*>(Wg1 + i * 4);
  __syncthreads();
  int lane = t & 63, wv = t >> 6;
  int half = lane >> 5, l = lane & 31;
  float w2 = Wg2[l];
  float b2 = bg2[0];
  float b1v = bg1[l];
  for (int it = 0; it < 16; ++it) {
    int node = blockIdx.x * 128 + it * 8 + wv * 2 + half;
    if (node < NN) {
      const float* hr = Ho + (size_t)node * 128;
      float acc = b1v;
      for (int k = 0; k < 128; k += 4) {
        float4 hv = *reinterpret_cast<const float4*>(hr + k);
        acc += hv.x * sW[(k) * 32 + l];
        acc += hv.y * sW[(k + 1) * 32 + l];
        acc += hv.z * sW[(k + 2) * 32 + l];
        acc += hv.w * sW[(k + 3) * 32 + l];
      }
      float v = fmaxf(acc, 0.f) * w2;
#pragma unroll
      for (int off = 16; off > 0; off >>= 1) v += __shfl_down(v, off, 32);
      if (l == 0) gate[node] = fmaxf(v + b2, 0.f);
    }
  }
}

// ---------------------------------------------------------------- pooling
__global__ void k_bounds(const int* __restrict__ batch0,
                         const int* __restrict__ batch1,
                         int* __restrict__ starts, int* __restrict__ ends) {
  int s = blockIdx.x;
  const int* batch = s ? batch1 : batch0;
  int g = threadIdx.x;
  if (g >= NB) return;
  int lo = 0, hi = NN;
  while (lo < hi) { int mid = (lo + hi) >> 1; if (batch[mid] < g) lo = mid + 1; else hi = mid; }
  starts[s * NB + g] = lo;
  lo = 0; hi = NN;
  while (lo < hi) { int mid = (lo + hi) >> 1; if (batch[mid] < g + 1) lo = mid + 1; else hi = mid; }
  ends[s * NB + g] = lo;
}

__global__ __launch_bounds__(256) void k_gstat(const float* __restrict__ gate_,
                                               const int* __restrict__ starts,
                                               const int* __restrict__ ends,
                                               float* __restrict__ gm,
                                               float* __restrict__ dn) {
  int sd = blockIdx.y;
  int b = blockIdx.x;
  const float* gate = gate_ + (size_t)sd * NN;
  __shared__ float red[256];
  int t = threadIdx.x;
  int s = starts[sd * NB + b], en = ends[sd * NB + b];
  float m = -3.402823e38f;
  for (int i = s + t; i < en; i += 256) m = fmaxf(m, gate[i]);
  red[t] = m;
  __syncthreads();
  for (int off = 128; off > 0; off >>= 1) {
    if (t < off) red[t] = fmaxf(red[t], red[t + off]);
    __syncthreads();
  }
  float gmax = red[0];
  __syncthreads();
  float ds = 0;
  for (int i = s + t; i < en; i += 256) ds += expf(gate[i] - gmax);
  red[t] = ds;
  __syncthreads();
  for (int off = 128; off > 0; off >>= 1) {
    if (t < off) red[t] += red[t + off];
    __syncthreads();
  }
  if (t == 0) {
    gm[sd * NB + b] = gmax;
    dn[sd * NB + b] = red[0];
  }
}

#define SPL 8
__global__ __launch_bounds__(256) void k_poolsum(const float* __restrict__ Ho_,
                                                 const float* __restrict__ gate_,
                                                 const int* __restrict__ starts,
                                                 const int* __restrict__ ends,
                                                 const float* __restrict__ gm,
                                                 const float* __restrict__ dn,
                                                 float* __restrict__ e) {
  int sd = blockIdx.y;
  int b = blockIdx.x;
  int z = blockIdx.z;
  const float* Ho = Ho_ + (size_t)sd * NN * HH;
  const float* gate = gate_ + (size_t)sd * NN;
  __shared__ float red[256];
  int t = threadIdx.x;
  int s = starts[sd * NB + b], en = ends[sd * NB + b];
  int len = en - s;
  if (len <= 0) return;  // e pre-zeroed by memset
  int chunk = (len + SPL - 1) / SPL;
  int i0 = s + z * chunk;
  int i1 = min(en, i0 + chunk);
  if (i0 >= i1) return;
  float gmax = gm[sd * NB + b];
  float invdn = 1.0f / dn[sd * NB + b];
  int c = t & 127, half = t >> 7;
  float acc = 0;
  for (int i = i0 + half; i < i1; i += 2)
    acc += expf(gate[i] - gmax) * Ho[(size_t)i * 128 + c];
  red[t] = acc;
  __syncthreads();
  if (t < 128)
    atomicAdd(&e[(size_t)sd * NB * HH + (size_t)b * HH + t],
              (red[t] + red[t + 128]) * invdn);
}

// ---------------------------------------------------------------- final MLP
__global__ void k_final(const float* __restrict__ e, const float* __restrict__ Wf1,
                        const float* __restrict__ bf1, const float* __restrict__ Wf2,
                        const float* __restrict__ bf2, float* __restrict__ out) {
  int b = blockIdx.x, j = threadIdx.x;  // 64 threads
  float acc = bf1[j];
  const float* e1 = e + (size_t)b * 128;
  const float* e2 = e + (size_t)NB * 128 + (size_t)b * 128;
  for (int k = 0; k < 128; ++k) {
    float d = fabsf(e1[k] - e2[k]);
    acc += d * Wf1[k * 64 + j];
  }
  float v = fmaxf(acc, 0.f) * Wf2[j];
#pragma unroll
  for (int off = 32; off > 0; off >>= 1) v += __shfl_down(v, off, 64);
  if (j == 0) out[b] = v + bf2[0];
}

// ---------------------------------------------------------------- launch
extern "C" void kernel_launch(void* const* d_in, const int* in_sizes, int n_in,
                              void* d_out, int out_size, void* d_ws, size_t ws_size,
                              hipStream_t stream) {
  const float* x0 = (const float*)d_in[0];
  const float* x1 = (const float*)d_in[1];
  const int* ei0 = (const int*)d_in[2];
  const int* ei1 = (const int*)d_in[3];
  const int* batch0 = (const int*)d_in[4];
  const int* batch1 = (const int*)d_in[5];
  const float* W1r = (const float*)d_in[6];
  const float* W1s = (const float*)d_in[7];
  const float* b1 = (const float*)d_in[8];
  const float* g1 = (const float*)d_in[9];
  const float* be1 = (const float*)d_in[10];
  const float* W2r = (const float*)d_in[11];
  const float* W2s = (const float*)d_in[12];
  const float* b2 = (const float*)d_in[13];
  const float* g2 = (const float*)d_in[14];
  const float* be2 = (const float*)d_in[15];
  const float* W3r = (const float*)d_in[16];
  const float* W3s = (const float*)d_in[17];
  const float* b3 = (const float*)d_in[18];
  const float* g3 = (const float*)d_in[19];
  const float* be3 = (const float*)d_in[20];
  const float* Wg1 = (const float*)d_in[21];
  const float* bg1 = (const float*)d_in[22];
  const float* Wg2 = (const float*)d_in[23];
  const float* bg2 = (const float*)d_in[24];
  const float* Wf1 = (const float*)d_in[25];
  const float* bf1 = (const float*)d_in[26];
  const float* Wf2 = (const float*)d_in[27];
  const float* bf2 = (const float*)d_in[28];

  char* p = (char*)d_ws;
  auto alloc = [&](size_t bytes) {
    void* r = (void*)p;
    p += (bytes + 255) & ~(size_t)255;
    return r;
  };
  int* counts = (int*)alloc((size_t)2 * NN * 4);
  int* rowptr = (int*)alloc((size_t)2 * (NN + 1) * 4);
  int* cursor = (int*)alloc((size_t)2 * NN * 4);
  unsigned short* col = (unsigned short*)alloc((size_t)2 * NE * 2);
  int* bsum = (int*)alloc(2 * SCB * 4);
  int* boff = (int*)alloc(2 * SCB * 4);
  int* starts = (int*)alloc(2 * NB * 4);
  int* ends = (int*)alloc(2 * NB * 4);
  float* stats = (float*)alloc(2 * 256 * 4);
  float* ss = (float*)alloc(2 * 256 * 4);
  float* gate = (float*)alloc((size_t)2 * NN * 4);
  float* gm = (float*)alloc(2 * NB * 4);
  float* dn = (float*)alloc(2 * NB * 4);
  float* ebuf = (float*)alloc((size_t)2 * NB * HH * 4);
  float* bufA = (float*)alloc((size_t)2 * NN * HH * 4);
  float* bufB = (float*)alloc((size_t)2 * NN * HH * 4);
  float* bufC = (float*)alloc((size_t)2 * NN * HH * 4);

  // ---- CSR build (both sides)
  hipMemsetAsync(counts, 0, (size_t)2 * NN * 4, stream);
  k_hist<<<dim3((NE + 255) / 256, 2), 256, 0, stream>>>(ei0, ei1, counts);
  k_scan1<<<dim3(SCB, 2), 256, 0, stream>>>(counts, rowptr, bsum);
  k_scan2<<<2, 256, 0, stream>>>(bsum, boff, rowptr);
  k_scan3<<<dim3(SCB, 2), 256, 0, stream>>>(rowptr, cursor, boff);
  k_scatter<<<dim3((NE + 255) / 256, 2), 256, 0, stream>>>(ei0, ei1, cursor, col);

  // ---- layer 1: F=38 -> 128
  k_agg<38><<<dim3(15000, 2), 256, 0, stream>>>(x0, x1, rowptr, col, bufA);
  hipMemsetAsync(stats, 0, 2 * 256 * 4, stream);
  k_gemm_mfma<false><<<dim3(938, 2), 256, 0, stream>>>(
      bufA, FIN, x0, x1, FIN, W1r, W1s, b1, FIN, bufB, stats);
  k_bnfin<<<2, 128, 0, stream>>>(stats, g1, be1, ss);
  k_bnrelu<<<dim3(7500, 2), 256, 0, stream>>>(bufB, ss);

  // ---- layer 2: 128 -> 128
  k_agg<128><<<dim3(15000, 2), 256, 0, stream>>>(bufB, bufB + (size_t)NN * HH,
                                                 rowptr, col, bufA);
  hipMemsetAsync(stats, 0, 2 * 256 * 4, stream);
  k_gemm_mfma<true><<<dim3(938, 2), 256, 0, stream>>>(
      bufA, HH, bufB, bufB + (size_t)NN * HH, HH, W2r, W2s, b2, HH, bufC, stats);
  k_bnfin<<<2, 128, 0, stream>>>(stats, g2, be2, ss);
  k_bnrelu<<<dim3(7500, 2), 256, 0, stream>>>(bufC, ss);

  // ---- layer 3: 128 -> 128
  k_agg<128><<<dim3(15000, 2), 256, 0, stream>>>(bufC, bufC + (size_t)NN * HH,
                                                 rowptr, col, bufA);
  hipMemsetAsync(stats, 0, 2 * 256 * 4, stream);
  k_gemm_mfma<true><<<dim3(938, 2), 256, 0, stream>>>(
      bufA, HH, bufC, bufC + (size_t)NN * HH, HH, W3r, W3s, b3, HH, bufB, stats);
  k_bnfin<<<2, 128, 0, stream>>>(stats, g3, be3, ss);
  k_bnrelu<<<dim3(7500, 2), 256, 0, stream>>>(bufB, ss);

  // ---- gate + attention pool (both sides), parallel pooling
  k_gate<<<dim3(469, 2), 256, 0, stream>>>(bufB, Wg1, bg1, Wg2, bg2, gate);
  k_bounds<<<2, 32, 0, stream>>>(batch0, batch1, starts, ends);
  hipMemsetAsync(ebuf, 0, (size_t)2 * NB * HH * 4, stream);
  k_gstat<<<dim3(NB, 2), 256, 0, stream>>>(gate, starts, ends, gm, dn);
  k_poolsum<<<dim3(NB, 2, SPL), 256, 0, stream>>>(bufB, gate, starts, ends, gm, dn,
                                                  ebuf);

  k_final<<<NB, 64, 0, stream>>>(ebuf, Wf1, bf1, Wf2, bf2, (float*)d_out);
}

// Round 12
// 1208.972 us; speedup vs baseline: 1.5949x; 1.0427x over previous
//
#include <hip/hip_runtime.h>
#include <cstdint>
#include <cstddef>

#define NN 60000
#define NE 960000
#define NB 32
#define FIN 38
#define HH 128
#define SCB 235  // scan blocks/side: 235*256 = 60160 >= NN

typedef short bf16x8 __attribute__((ext_vector_type(8)));
typedef float f32x4 __attribute__((ext_vector_type(4)));

__device__ __forceinline__ unsigned short f2bf(float x) {
  unsigned u = __builtin_bit_cast(unsigned, x);
  u = u + 0x7fffu + ((u >> 16) & 1u);
  return (unsigned short)(u >> 16);
}
__device__ __forceinline__ float bf2f(unsigned short h) {
  unsigned u = ((unsigned)h) << 16;
  return __builtin_bit_cast(float, u);
}

// ---------------------------------------------------------------- CSR build
__global__ __launch_bounds__(256) void k_hist(const int* __restrict__ ei0,
                                              const int* __restrict__ ei1,
                                              int* __restrict__ counts) {
  int s = blockIdx.y;
  const int* ei = s ? ei1 : ei0;
  int i = blockIdx.x * 256 + threadIdx.x;
  if (i < NE) atomicAdd(&counts[s * NN + ei[NE + i]], 1);
}

__global__ __launch_bounds__(256) void k_scan1(const int* __restrict__ counts_,
                                               int* __restrict__ rowptr_,
                                               int* __restrict__ bsum) {
  int s = blockIdx.y, b = blockIdx.x, t = threadIdx.x;
  int idx = b * 256 + t;
  const int* counts = counts_ + (size_t)s * NN;
  int* rowptr = rowptr_ + (size_t)s * (NN + 1);
  __shared__ int sm[256];
  int c = (idx < NN) ? counts[idx] : 0;
  sm[t] = c;
  __syncthreads();
  for (int off = 1; off < 256; off <<= 1) {
    int v = (t >= off) ? sm[t - off] : 0;
    __syncthreads();
    sm[t] += v;
    __syncthreads();
  }
  if (idx < NN) rowptr[idx] = sm[t] - c;
  if (t == 255) bsum[s * SCB + b] = sm[255];
}

__global__ __launch_bounds__(256) void k_scan2(const int* __restrict__ bsum,
                                               int* __restrict__ boff,
                                               int* __restrict__ rowptr_) {
  int s = blockIdx.x, t = threadIdx.x;
  __shared__ int sm[256];
  int v = (t < SCB) ? bsum[s * SCB + t] : 0;
  sm[t] = v;
  __syncthreads();
  for (int off = 1; off < 256; off <<= 1) {
    int u = (t >= off) ? sm[t - off] : 0;
    __syncthreads();
    sm[t] += u;
    __syncthreads();
  }
  if (t < SCB) boff[s * SCB + t] = sm[t] - v;
  if (t == 255) rowptr_[(size_t)s * (NN + 1) + NN] = sm[255];
}

__global__ __launch_bounds__(256) void k_scan3(int* __restrict__ rowptr_,
                                               int* __restrict__ cursor_,
                                               const int* __restrict__ boff) {
  int s = blockIdx.y, b = blockIdx.x, t = threadIdx.x;
  int idx = b * 256 + t;
  if (idx < NN) {
    int v = rowptr_[(size_t)s * (NN + 1) + idx] + boff[s * SCB + b];
    rowptr_[(size_t)s * (NN + 1) + idx] = v;
    cursor_[(size_t)s * NN + idx] = v;
  }
}

__global__ __launch_bounds__(256) void k_scatter(const int* __restrict__ ei0,
                                                 const int* __restrict__ ei1,
                                                 int* __restrict__ cursor,
                                                 unsigned short* __restrict__ col) {
  int s = blockIdx.y;
  const int* ei = s ? ei1 : ei0;
  int i = blockIdx.x * 256 + threadIdx.x;
  if (i < NE) {
    int dst = ei[NE + i];
    int src = ei[i];
    int pos = atomicAdd(&cursor[s * NN + dst], 1);
    col[(size_t)s * NE + pos] = (unsigned short)src;
  }
}

// ---------------------------------------------------------------- aggregation
template <int W>
__global__ __launch_bounds__(256) void k_agg(const float* __restrict__ h0,
                                             const float* __restrict__ h1,
                                             const int* __restrict__ rowptr_,
                                             const unsigned short* __restrict__ col_,
                                             float* __restrict__ agg_) {
  int s = blockIdx.y;
  const float* h = s ? h1 : h0;
  const int* rowptr = rowptr_ + (size_t)s * (NN + 1);
  const unsigned short* col = col_ + (size_t)s * NE;
  float* agg = agg_ + (size_t)s * NN * W;
  int wave = threadIdx.x >> 6;
  int lane = threadIdx.x & 63;
  int node = blockIdx.x * 4 + wave;
  if (node >= NN) return;
  int s0 = rowptr[node], s1 = rowptr[node + 1];
  if (W == 128) {
    float2 acc = make_float2(0.f, 0.f);
    const float* hp = h + (lane << 1);
    int j = s0;
    for (; j + 3 < s1; j += 4) {
      int a0 = col[j], a1 = col[j + 1], a2 = col[j + 2], a3 = col[j + 3];
      float2 v0 = *reinterpret_cast<const float2*>(hp + (size_t)a0 * 128);
      float2 v1 = *reinterpret_cast<const float2*>(hp + (size_t)a1 * 128);
      float2 v2 = *reinterpret_cast<const float2*>(hp + (size_t)a2 * 128);
      float2 v3 = *reinterpret_cast<const float2*>(hp + (size_t)a3 * 128);
      acc.x += (v0.x + v1.x) + (v2.x + v3.x);
      acc.y += (v0.y + v1.y) + (v2.y + v3.y);
    }
    for (; j < s1; ++j) {
      int a0 = col[j];
      float2 v0 = *reinterpret_cast<const float2*>(hp + (size_t)a0 * 128);
      acc.x += v0.x;
      acc.y += v0.y;
    }
    *reinterpret_cast<float2*>(agg + (size_t)node * 128 + (lane << 1)) = acc;
  } else {
    float2 acc = make_float2(0.f, 0.f);
    if (lane < 19) {
      const float* hp = h + (lane << 1);
      int j = s0;
      for (; j + 1 < s1; j += 2) {
        int a0 = col[j], a1 = col[j + 1];
        float2 v0 = *reinterpret_cast<const float2*>(hp + (size_t)a0 * W);
        float2 v1 = *reinterpret_cast<const float2*>(hp + (size_t)a1 * W);
        acc.x += v0.x + v1.x;
        acc.y += v0.y + v1.y;
      }
      if (j < s1) {
        float2 v = *reinterpret_cast<const float2*>(hp + (size_t)col[j] * W);
        acc.x += v.x;
        acc.y += v.y;
      }
      *reinterpret_cast<float2*>(agg + (size_t)node * W + (lane << 1)) = acc;
    }
  }
}

// ---------------------------------------------------------------- weight prep
// Converts Wr/Ws (K x 128 f32) into the exact swizzled split-bf16 LDS image
// per K-step: img[ks][32KB] = [mat0 hi 8KB][mat1 hi 8KB][mat0 lo 8KB][mat1 lo
// 8KB], byte off within plane = ((c<<6)+(kq<<3)) ^ ((c&7)<<4). Done ONCE per
// layer; GEMM stages weights via a linear conflict-free copy.
__global__ __launch_bounds__(256) void k_wprep(const float* __restrict__ Wr,
                                               const float* __restrict__ Ws,
                                               int K, unsigned char* __restrict__ img) {
  int ks = blockIdx.x;
  int t = threadIdx.x;
  unsigned char* dst = img + (size_t)ks * 32768;
  int kq = t >> 5;
  int c0 = (t & 31) << 2;
  float wf[2][4][4];
#pragma unroll
  for (int kk = 0; kk < 4; ++kk) {
    int gk = (ks << 5) + (kq << 2) + kk;
    float4 vr = make_float4(0, 0, 0, 0), vs = vr;
    if (gk < K) {
      vr = *reinterpret_cast<const float4*>(Wr + (size_t)gk * HH + c0);
      vs = *reinterpret_cast<const float4*>(Ws + (size_t)gk * HH + c0);
    }
    wf[0][kk][0] = vr.x; wf[0][kk][1] = vr.y; wf[0][kk][2] = vr.z; wf[0][kk][3] = vr.w;
    wf[1][kk][0] = vs.x; wf[1][kk][1] = vs.y; wf[1][kk][2] = vs.z; wf[1][kk][3] = vs.w;
  }
#pragma unroll
  for (int m = 0; m < 2; ++m) {
#pragma unroll
    for (int j = 0; j < 4; ++j) {
      int c = c0 + j;
      unsigned h0 = f2bf(wf[m][0][j]), h1 = f2bf(wf[m][1][j]);
      unsigned h2 = f2bf(wf[m][2][j]), h3 = f2bf(wf[m][3][j]);
      unsigned l0 = f2bf(wf[m][0][j] - bf2f((unsigned short)h0));
      unsigned l1 = f2bf(wf[m][1][j] - bf2f((unsigned short)h1));
      unsigned l2 = f2bf(wf[m][2][j] - bf2f((unsigned short)h2));
      unsigned l3 = f2bf(wf[m][3][j] - bf2f((unsigned short)h3));
      uint2 hv = make_uint2(h0 | (h1 << 16), h2 | (h3 << 16));
      uint2 lv = make_uint2(l0 | (l1 << 16), l2 | (l3 << 16));
      int off = ((c << 6) + (kq << 3)) ^ ((c & 7) << 4);
      *reinterpret_cast<uint2*>(dst + m * 8192 + off) = hv;
      *reinterpret_cast<uint2*>(dst + 16384 + m * 8192 + off) = lv;
    }
  }
}

// ---------------------------------------------------------------- MFMA GEMM
// Tile 128 rows x 128 cols, 8 waves (512 thr), wave = 32r x 64c. Weights come
// pre-converted/swizzled from wimg (L2-resident) via linear copy.
template <bool VEC>
__global__ __launch_bounds__(512) void k_gemm_mfma(
    const float* __restrict__ A_, int lda, const float* __restrict__ X0,
    const float* __restrict__ X1, int ldx, const unsigned char* __restrict__ wimg,
    const float* __restrict__ bias, int K, float* __restrict__ Z_,
    float* __restrict__ stats_) {
  int side = blockIdx.y;
  const float* A = A_ + (size_t)side * NN * lda;
  const float* X = side ? X1 : X0;
  float* Z = Z_ + (size_t)side * NN * HH;
  float* stats = stats_ + (size_t)side * 256;

  __shared__ __align__(16) unsigned char sAh[128 * 64];
  __shared__ __align__(16) unsigned char sAl[128 * 64];
  __shared__ __align__(16) unsigned char sXh[128 * 64];
  __shared__ __align__(16) unsigned char sXl[128 * 64];
  __shared__ __align__(16) unsigned char sW[4 * 8192];  // [m0h][m1h][m0l][m1l]

  int t = threadIdx.x;
  int l = t & 63;
  int wid = t >> 6;          // 0..7
  int wr = wid >> 1, wc = wid & 1;
  int row0 = blockIdx.x * 128;

  f32x4 acc[2][4];
#pragma unroll
  for (int rt = 0; rt < 2; ++rt)
#pragma unroll
    for (int ct = 0; ct < 4; ++ct) acc[rt][ct] = (f32x4)(0.f);

  int nK = (K + 31) >> 5;
  for (int ks = 0; ks < nK; ++ks) {
    // ---- stage A/X tile: 128 rows x 32 k, split hi/lo bf16
    {
      int r = t >> 2;          // 0..127
      int kc = (t & 3) << 3;   // 8 k per thread
      int grow = row0 + r;
      float av[8], xv[8];
      if (VEC) {
        float4 a0 = make_float4(0, 0, 0, 0), a1 = a0, x0 = a0, x1 = a0;
        if (grow < NN) {
          const float* pa = A + (size_t)grow * lda + (ks << 5) + kc;
          const float* px = X + (size_t)grow * ldx + (ks << 5) + kc;
          a0 = *reinterpret_cast<const float4*>(pa);
          a1 = *reinterpret_cast<const float4*>(pa + 4);
          x0 = *reinterpret_cast<const float4*>(px);
          x1 = *reinterpret_cast<const float4*>(px + 4);
        }
        av[0] = a0.x; av[1] = a0.y; av[2] = a0.z; av[3] = a0.w;
        av[4] = a1.x; av[5] = a1.y; av[6] = a1.z; av[7] = a1.w;
        xv[0] = x0.x; xv[1] = x0.y; xv[2] = x0.z; xv[3] = x0.w;
        xv[4] = x1.x; xv[5] = x1.y; xv[6] = x1.z; xv[7] = x1.w;
      } else {
#pragma unroll
        for (int e = 0; e < 8; ++e) {
          int gk = (ks << 5) + kc + e;
          bool ok = (grow < NN) && (gk < K);
          av[e] = ok ? A[(size_t)grow * lda + gk] : 0.f;
          xv[e] = ok ? X[(size_t)grow * ldx + gk] : 0.f;
        }
      }
      bf16x8 ah, al, xh, xl;
#pragma unroll
      for (int e = 0; e < 8; ++e) {
        unsigned short h = f2bf(av[e]);
        ah[e] = (short)h;
        al[e] = (short)f2bf(av[e] - bf2f(h));
        h = f2bf(xv[e]);
        xh[e] = (short)h;
        xl[e] = (short)f2bf(xv[e] - bf2f(h));
      }
      int off = ((r << 6) + (kc << 1)) ^ ((r & 7) << 4);
      *reinterpret_cast<bf16x8*>(sAh + off) = ah;
      *reinterpret_cast<bf16x8*>(sAl + off) = al;
      *reinterpret_cast<bf16x8*>(sXh + off) = xh;
      *reinterpret_cast<bf16x8*>(sXl + off) = xl;
    }
    // ---- stage weights: linear conflict-free copy of the prepped image
    {
      const uint4* src = reinterpret_cast<const uint4*>(wimg + (size_t)ks * 32768);
      uint4* dst = reinterpret_cast<uint4*>(sW);
#pragma unroll
      for (int i = 0; i < 4; ++i) {
        int idx = t + i * 512;  // 2048 x 16B = 32KB
        dst[idx] = src[idx];
      }
    }
    __syncthreads();
    // ---- MFMA phase
    bf16x8 fah[2], fal[2], fxh[2], fxl[2];
    int ko = (l >> 4) << 4;
#pragma unroll
    for (int rt = 0; rt < 2; ++rt) {
      int rr = (wr << 5) + (rt << 4) + (l & 15);
      int off = ((rr << 6) + ko) ^ ((rr & 7) << 4);
      fah[rt] = *reinterpret_cast<const bf16x8*>(sAh + off);
      fal[rt] = *reinterpret_cast<const bf16x8*>(sAl + off);
      fxh[rt] = *reinterpret_cast<const bf16x8*>(sXh + off);
      fxl[rt] = *reinterpret_cast<const bf16x8*>(sXl + off);
    }
#pragma unroll
    for (int ct = 0; ct < 4; ++ct) {
      int cc = (wc << 6) + (ct << 4) + (l & 15);
      int off = ((cc << 6) + ko) ^ ((cc & 7) << 4);
      bf16x8 brh = *reinterpret_cast<const bf16x8*>(sW + off);           // m0 hi
      bf16x8 bsh = *reinterpret_cast<const bf16x8*>(sW + 8192 + off);    // m1 hi
      bf16x8 brl = *reinterpret_cast<const bf16x8*>(sW + 16384 + off);   // m0 lo
      bf16x8 bsl = *reinterpret_cast<const bf16x8*>(sW + 24576 + off);   // m1 lo
#pragma unroll
      for (int rt = 0; rt < 2; ++rt) {
        f32x4 c = acc[rt][ct];
        c = __builtin_amdgcn_mfma_f32_16x16x32_bf16(fah[rt], brh, c, 0, 0, 0);
        c = __builtin_amdgcn_mfma_f32_16x16x32_bf16(fah[rt], brl, c, 0, 0, 0);
        c = __builtin_amdgcn_mfma_f32_16x16x32_bf16(fal[rt], brh, c, 0, 0, 0);
        c = __builtin_amdgcn_mfma_f32_16x16x32_bf16(fxh[rt], bsh, c, 0, 0, 0);
        c = __builtin_amdgcn_mfma_f32_16x16x32_bf16(fxh[rt], bsl, c, 0, 0, 0);
        c = __builtin_amdgcn_mfma_f32_16x16x32_bf16(fxl[rt], bsh, c, 0, 0, 0);
        acc[rt][ct] = c;
      }
    }
    __syncthreads();
  }

  // ---- epilogue: bias, store Z, per-channel stats
  float ps[4] = {0, 0, 0, 0}, pq[4] = {0, 0, 0, 0};
#pragma unroll
  for (int ct = 0; ct < 4; ++ct) {
    int col = (wc << 6) + (ct << 4) + (l & 15);
    float b = bias[col];
#pragma unroll
    for (int rt = 0; rt < 2; ++rt) {
      int rbase = row0 + (wr << 5) + (rt << 4) + ((l >> 4) << 2);
      f32x4 v = acc[rt][ct];
#pragma unroll
      for (int rg = 0; rg < 4; ++rg) {
        int row = rbase + rg;
        if (row < NN) {
          float z = v[rg] + b;
          Z[(size_t)row * HH + col] = z;
          ps[ct] += z;
          pq[ct] += z * z;
        }
      }
    }
  }
#pragma unroll
  for (int ct = 0; ct < 4; ++ct) {
    ps[ct] += __shfl_xor(ps[ct], 16, 64);
    ps[ct] += __shfl_xor(ps[ct], 32, 64);
    pq[ct] += __shfl_xor(pq[ct], 16, 64);
    pq[ct] += __shfl_xor(pq[ct], 32, 64);
  }
  if (l < 16) {
#pragma unroll
    for (int ct = 0; ct < 4; ++ct) {
      int col = (wc << 6) + (ct << 4) + l;
      atomicAdd(&stats[col], ps[ct]);
      atomicAdd(&stats[HH + col], pq[ct]);
    }
  }
}

// ---------------------------------------------------------------- BN
__global__ void k_bnfin(const float* __restrict__ stats_, const float* __restrict__ g,
                        const float* __restrict__ be, float* __restrict__ ss_) {
  int s = blockIdx.x;
  const float* stats = stats_ + (size_t)s * 256;
  float* ss = ss_ + (size_t)s * 256;
  int c = threadIdx.x;
  if (c < HH) {
    float mu = stats[c] * (1.0f / NN);
    float var = stats[HH + c] * (1.0f / NN) - mu * mu;
    float inv = 1.0f / sqrtf(var + 1e-5f);
    float sc = g[c] * inv;
    ss[c] = sc;
    ss[HH + c] = be[c] - mu * sc;
  }
}

__global__ __launch_bounds__(256) void k_bnrelu(float* __restrict__ ZH_,
                                                const float* __restrict__ ss_) {
  int s = blockIdx.y;
  float* ZH = ZH_ + (size_t)s * NN * HH;
  const float* ss = ss_ + (size_t)s * 256;
  size_t i = (size_t)blockIdx.x * 256 + threadIdx.x;
  float4 z = *reinterpret_cast<float4*>(ZH + i * 4);
  int c = (int)((i * 4) & 127);
  float4 sc = *reinterpret_cast<const float4*>(ss + c);
  float4 sh = *reinterpret_cast<const float4*>(ss + HH + c);
  z.x = fmaxf(z.x * sc.x + sh.x, 0.f);
  z.y = fmaxf(z.y * sc.y + sh.y, 0.f);
  z.z = fmaxf(z.z * sc.z + sh.z, 0.f);
  z.w = fmaxf(z.w * sc.w + sh.w, 0.f);
  *reinterpret_cast<float4*>(ZH + i * 4) = z;
}

// ---------------------------------------------------------------- gate MLP
__global__ __launch_bounds__(256) void k_gate(const float* __restrict__ Ho_,
                                              const float* __restrict__ Wg1,
                                              const float* __restrict__ bg1,
                                              const float* __restrict__ Wg2,
                                              const float* __restrict__ bg2,
                                              float* __restrict__ gate_) {
  int s = blockIdx.y;
  const float* Ho = Ho_ + (size_t)s * NN * HH;
  float* gate = gate_ + (size_t)s * NN;
  __shared__ float sW[128 * 32];
  int t = threadIdx.x;
  for (int i = t; i < 128 * 32 / 4; i += 256)
    *reinterpret_cast<float4*>(&sW[i * 4]) =
        *reinterpret_cast<const float4*>(Wg1 + i * 4);
  __syncthreads();
  int lane = t & 63, wv = t >> 6;
  int half = lane >> 5, l = lane & 31;
  float w2 = Wg2[l];
  float b2 = bg2[0];
  float b1v = bg1[l];
  for (int it = 0; it < 16; ++it) {
    int node = blockIdx.x * 128 + it * 8 + wv * 2 + half;
    if (node < NN) {
      const float* hr = Ho + (size_t)node * 128;
      float acc = b1v;
      for (int k = 0; k < 128; k += 4) {
        float4 hv = *reinterpret_cast<const float4*>(hr + k);
        acc += hv.x * sW[(k) * 32 + l];
        acc += hv.y * sW[(k + 1) * 32 + l];
        acc += hv.z * sW[(k + 2) * 32 + l];
        acc += hv.w * sW[(k + 3) * 32 + l];
      }
      float v = fmaxf(acc, 0.f) * w2;
#pragma unroll
      for (int off = 16; off > 0; off >>= 1) v += __shfl_down(v, off, 32);
      if (l == 0) gate[node] = fmaxf(v + b2, 0.f);
    }
  }
}

// ---------------------------------------------------------------- pooling
__global__ void k_bounds(const int* __restrict__ batch0,
                         const int* __restrict__ batch1,
                         int* __restrict__ starts, int* __restrict__ ends) {
  int s = blockIdx.x;
  const int* batch = s ? batch1 : batch0;
  int g = threadIdx.x;
  if (g >= NB) return;
  int lo = 0, hi = NN;
  while (lo < hi) { int mid = (lo + hi) >> 1; if (batch[mid] < g) lo = mid + 1; else hi = mid; }
  starts[s * NB + g] = lo;
  lo = 0; hi = NN;
  while (lo < hi) { int mid = (lo + hi) >> 1; if (batch[mid] < g + 1) lo = mid + 1; else hi = mid; }
  ends[s * NB + g] = lo;
}

__global__ __launch_bounds__(256) void k_gstat(const float* __restrict__ gate_,
                                               const int* __restrict__ starts,
                                               const int* __restrict__ ends,
                                               float* __restrict__ gm,
                                               float* __restrict__ dn) {
  int sd = blockIdx.y;
  int b = blockIdx.x;
  const float* gate = gate_ + (size_t)sd * NN;
  __shared__ float red[256];
  int t = threadIdx.x;
  int s = starts[sd * NB + b], en = ends[sd * NB + b];
  float m = -3.402823e38f;
  for (int i = s + t; i < en; i += 256) m = fmaxf(m, gate[i]);
  red[t] = m;
  __syncthreads();
  for (int off = 128; off > 0; off >>= 1) {
    if (t < off) red[t] = fmaxf(red[t], red[t + off]);
    __syncthreads();
  }
  float gmax = red[0];
  __syncthreads();
  float ds = 0;
  for (int i = s + t; i < en; i += 256) ds += expf(gate[i] - gmax);
  red[t] = ds;
  __syncthreads();
  for (int off = 128; off > 0; off >>= 1) {
    if (t < off) red[t] += red[t + off];
    __syncthreads();
  }
  if (t == 0) {
    gm[sd * NB + b] = gmax;
    dn[sd * NB + b] = red[0];
  }
}

#define SPL 8
__global__ __launch_bounds__(256) void k_poolsum(const float* __restrict__ Ho_,
                                                 const float* __restrict__ gate_,
                                                 const int* __restrict__ starts,
                                                 const int* __restrict__ ends,
                                                 const float* __restrict__ gm,
                                                 const float* __restrict__ dn,
                                                 float* __restrict__ e) {
  int sd = blockIdx.y;
  int b = blockIdx.x;
  int z = blockIdx.z;
  const float* Ho = Ho_ + (size_t)sd * NN * HH;
  const float* gate = gate_ + (size_t)sd * NN;
  __shared__ float red[256];
  int t = threadIdx.x;
  int s = starts[sd * NB + b], en = ends[sd * NB + b];
  int len = en - s;
  if (len <= 0) return;  // e pre-zeroed by memset
  int chunk = (len + SPL - 1) / SPL;
  int i0 = s + z * chunk;
  int i1 = min(en, i0 + chunk);
  if (i0 >= i1) return;
  float gmax = gm[sd * NB + b];
  float invdn = 1.0f / dn[sd * NB + b];
  int c = t & 127, half = t >> 7;
  float acc = 0;
  for (int i = i0 + half; i < i1; i += 2)
    acc += expf(gate[i] - gmax) * Ho[(size_t)i * 128 + c];
  red[t] = acc;
  __syncthreads();
  if (t < 128)
    atomicAdd(&e[(size_t)sd * NB * HH + (size_t)b * HH + t],
              (red[t] + red[t + 128]) * invdn);
}

// ---------------------------------------------------------------- final MLP
__global__ void k_final(const float* __restrict__ e, const float* __restrict__ Wf1,
                        const float* __restrict__ bf1, const float* __restrict__ Wf2,
                        const float* __restrict__ bf2, float* __restrict__ out) {
  int b = blockIdx.x, j = threadIdx.x;  // 64 threads
  float acc = bf1[j];
  const float* e1 = e + (size_t)b * 128;
  const float* e2 = e + (size_t)NB * 128 + (size_t)b * 128;
  for (int k = 0; k < 128; ++k) {
    float d = fabsf(e1[k] - e2[k]);
    acc += d * Wf1[k * 64 + j];
  }
  float v = fmaxf(acc, 0.f) * Wf2[j];
#pragma unroll
  for (int off = 32; off > 0; off >>= 1) v += __shfl_down(v, off, 64);
  if (j == 0) out[b] = v + bf2[0];
}

// ---------------------------------------------------------------- launch
extern "C" void kernel_launch(void* const* d_in, const int* in_sizes, int n_in,
                              void* d_out, int out_size, void* d_ws, size_t ws_size,
                              hipStream_t stream) {
  const float* x0 = (const float*)d_in[0];
  const float* x1 = (const float*)d_in[1];
  const int* ei0 = (const int*)d_in[2];
  const int* ei1 = (const int*)d_in[3];
  const int* batch0 = (const int*)d_in[4];
  const int* batch1 = (const int*)d_in[5];
  const float* W1r = (const float*)d_in[6];
  const float* W1s = (const float*)d_in[7];
  const float* b1 = (const float*)d_in[8];
  const float* g1 = (const float*)d_in[9];
  const float* be1 = (const float*)d_in[10];
  const float* W2r = (const float*)d_in[11];
  const float* W2s = (const float*)d_in[12];
  const float* b2 = (const float*)d_in[13];
  const float* g2 = (const float*)d_in[14];
  const float* be2 = (const float*)d_in[15];
  const float* W3r = (const float*)d_in[16];
  const float* W3s = (const float*)d_in[17];
  const float* b3 = (const float*)d_in[18];
  const float* g3 = (const float*)d_in[19];
  const float* be3 = (const float*)d_in[20];
  const float* Wg1 = (const float*)d_in[21];
  const float* bg1 = (const float*)d_in[22];
  const float* Wg2 = (const float*)d_in[23];
  const float* bg2 = (const float*)d_in[24];
  const float* Wf1 = (const float*)d_in[25];
  const float* bf1 = (const float*)d_in[26];
  const float* Wf2 = (const float*)d_in[27];
  const float* bf2 = (const float*)d_in[28];

  char* p = (char*)d_ws;
  auto alloc = [&](size_t bytes) {
    void* r = (void*)p;
    p += (bytes + 255) & ~(size_t)255;
    return r;
  };
  int* counts = (int*)alloc((size_t)2 * NN * 4);
  int* rowptr = (int*)alloc((size_t)2 * (NN + 1) * 4);
  int* cursor = (int*)alloc((size_t)2 * NN * 4);
  unsigned short* col = (unsigned short*)alloc((size_t)2 * NE * 2);
  int* bsum = (int*)alloc(2 * SCB * 4);
  int* boff = (int*)alloc(2 * SCB * 4);
  int* starts = (int*)alloc(2 * NB * 4);
  int* ends = (int*)alloc(2 * NB * 4);
  float* stats = (float*)alloc(2 * 256 * 4);
  float* ss = (float*)alloc(2 * 256 * 4);
  float* gate = (float*)alloc((size_t)2 * NN * 4);
  float* gm = (float*)alloc(2 * NB * 4);
  float* dn = (float*)alloc(2 * NB * 4);
  float* ebuf = (float*)alloc((size_t)2 * NB * HH * 4);
  unsigned char* wimg1 = (unsigned char*)alloc(2 * 32768);   // layer1: nK=2
  unsigned char* wimg2 = (unsigned char*)alloc(4 * 32768);   // layer2: nK=4
  unsigned char* wimg3 = (unsigned char*)alloc(4 * 32768);   // layer3: nK=4
  float* bufA = (float*)alloc((size_t)2 * NN * HH * 4);
  float* bufB = (float*)alloc((size_t)2 * NN * HH * 4);
  float* bufC = (float*)alloc((size_t)2 * NN * HH * 4);

  // ---- weight prep (once per layer, independent of everything else)
  k_wprep<<<2, 256, 0, stream>>>(W1r, W1s, FIN, wimg1);
  k_wprep<<<4, 256, 0, stream>>>(W2r, W2s, HH, wimg2);
  k_wprep<<<4, 256, 0, stream>>>(W3r, W3s, HH, wimg3);

  // ---- CSR build (both sides)
  hipMemsetAsync(counts, 0, (size_t)2 * NN * 4, stream);
  k_hist<<<dim3((NE + 255) / 256, 2), 256, 0, stream>>>(ei0, ei1, counts);
  k_scan1<<<dim3(SCB, 2), 256, 0, stream>>>(counts, rowptr, bsum);
  k_scan2<<<2, 256, 0, stream>>>(bsum, boff, rowptr);
  k_scan3<<<dim3(SCB, 2), 256, 0, stream>>>(rowptr, cursor, boff);
  k_scatter<<<dim3((NE + 255) / 256, 2), 256, 0, stream>>>(ei0, ei1, cursor, col);

  // ---- layer 1: F=38 -> 128
  k_agg<38><<<dim3(15000, 2), 256, 0, stream>>>(x0, x1, rowptr, col, bufA);
  hipMemsetAsync(stats, 0, 2 * 256 * 4, stream);
  k_gemm_mfma<false><<<dim3(469, 2), 512, 0, stream>>>(
      bufA, FIN, x0, x1, FIN, wimg1, b1, FIN, bufB, stats);
  k_bnfin<<<2, 128, 0, stream>>>(stats, g1, be1, ss);
  k_bnrelu<<<dim3(7500, 2), 256, 0, stream>>>(bufB, ss);

  // ---- layer 2: 128 -> 128
  k_agg<128><<<dim3(15000, 2), 256, 0, stream>>>(bufB, bufB + (size_t)NN * HH,
                                                 rowptr, col, bufA);
  hipMemsetAsync(stats, 0, 2 * 256 * 4, stream);
  k_gemm_mfma<true><<<dim3(469, 2), 512, 0, stream>>>(
      bufA, HH, bufB, bufB + (size_t)NN * HH, HH, wimg2, b2, HH, bufC, stats);
  k_bnfin<<<2, 128, 0, stream>>>(stats, g2, be2, ss);
  k_bnrelu<<<dim3(7500, 2), 256, 0, stream>>>(bufC, ss);

  // ---- layer 3: 128 -> 128
  k_agg<128><<<dim3(15000, 2), 256, 0, stream>>>(bufC, bufC + (size_t)NN * HH,
                                                 rowptr, col, bufA);
  hipMemsetAsync(stats, 0, 2 * 256 * 4, stream);
  k_gemm_mfma<true><<<dim3(469, 2), 512, 0, stream>>>(
      bufA, HH, bufC, bufC + (size_t)NN * HH, HH, wimg3, b3, HH, bufB, stats);
  k_bnfin<<<2, 128, 0, stream>>>(stats, g3, be3, ss);
  k_bnrelu<<<dim3(7500, 2), 256, 0, stream>>>(bufB, ss);

  // ---- gate + attention pool (both sides), parallel pooling
  k_gate<<<dim3(469, 2), 256, 0, stream>>>(bufB, Wg1, bg1, Wg2, bg2, gate);
  k_bounds<<<2, 32, 0, stream>>>(batch0, batch1, starts, ends);
  hipMemsetAsync(ebuf, 0, (size_t)2 * NB * HH * 4, stream);
  k_gstat<<<dim3(NB, 2), 256, 0, stream>>>(gate, starts, ends, gm, dn);
  k_poolsum<<<dim3(NB, 2, SPL), 256, 0, stream>>>(bufB, gate, starts, ends, gm, dn,
                                                  ebuf);

  k_final<<<NB, 64, 0, stream>>>(ebuf, Wf1, bf1, Wf2, bf2, (float*)d_out);
}